// Round 11
// baseline (235.850 us; speedup 1.0000x reference)
//
#include <hip/hip_runtime.h>
#include <hip/hip_bf16.h>
#include <math.h>

#define D 256
#define D_SEQ 1280
#define D_HEAD 48
#define N_HEAD 8
#define HDH 384        // N_HEAD * D_HEAD
#define N_NODE 2048
#define B_GRAPH 8
#define S_LEN 1024
#define LN_EPS 1e-5f
#define QSCALE (0.14433756729740643f * 1.4426950408889634f)  // 1/sqrt(48)*log2(e)
#define KVN 768        // fused K|V gemm output width
#define QGN 768        // fused Q|gate gemm output width
#define QROWS (N_NODE + 16)              // padded Q rows per head
#define TPG 40         // max 16-node tiles per graph
#define NWL (TPG * 8)  // strided worklist: wl[i*8+b]

typedef unsigned short u16;
typedef __attribute__((ext_vector_type(8))) short short8;
typedef __attribute__((ext_vector_type(4))) short short4v;
typedef __attribute__((ext_vector_type(4))) unsigned short ushort4v;
typedef __attribute__((ext_vector_type(4))) float floatx4;

__device__ __forceinline__ u16 f2bf(float f) {
    unsigned int x = __float_as_uint(f);
    x += 0x7fff + ((x >> 16) & 1);      // RNE to bf16
    return (u16)(x >> 16);
}

// async 16B-per-lane global->LDS DMA (wave-uniform LDS base + lane*16B)
__device__ __forceinline__ void load_lds16(const u16* g, u16* lds) {
    __builtin_amdgcn_global_load_lds(
        (const __attribute__((address_space(1))) unsigned int*)g,
        (__attribute__((address_space(3))) unsigned int*)lds, 16, 0, 0);
}

// ---------------------------------------------------------------------------
// ranges + graph-strided worklist: wl[i*8+b] = (b<<16)|n0, -1 if i >= ntiles(b).
// ---------------------------------------------------------------------------
__global__ void ranges_kernel(const int* __restrict__ batch, int* __restrict__ ranges,
                              int* __restrict__ wl) {
    int t = threadIdx.x;
    if (t <= B_GRAPH) {
        int lo = 0, hi = N_NODE;
        while (lo < hi) {
            int mid = (lo + hi) >> 1;
            if (batch[mid] < t) lo = mid + 1; else hi = mid;
        }
        ranges[t] = lo;
    }
    __syncthreads();
    if (t < B_GRAPH) {
        const int s = ranges[t];
        const int ntile = (ranges[t + 1] - s + 15) >> 4;
        for (int i = 0; i < TPG; ++i)
            wl[i * 8 + t] = (i < ntile) ? ((t << 16) | (s + i * 16)) : -1;
    }
}

// ---------------------------------------------------------------------------
__global__ __launch_bounds__(256)
void tobf16_kernel(const float* __restrict__ in, u16* __restrict__ out) {
    const size_t i = ((size_t)blockIdx.x * 256 + threadIdx.x) * 8;
    const float4 a = *(const float4*)&in[i];
    const float4 b = *(const float4*)&in[i + 4];
    union { u16 u[8]; int4 v; } p;
    p.u[0]=f2bf(a.x); p.u[1]=f2bf(a.y); p.u[2]=f2bf(a.z); p.u[3]=f2bf(a.w);
    p.u[4]=f2bf(b.x); p.u[5]=f2bf(b.y); p.u[6]=f2bf(b.z); p.u[7]=f2bf(b.w);
    *(int4*)&out[i] = p.v;
}

// ---------------------------------------------------------------------------
__global__ __launch_bounds__(256)
void ln_kernel(const float* __restrict__ node, const float* __restrict__ g,
               const float* __restrict__ b, u16* __restrict__ yb) {
    int n = blockIdx.x, t = threadIdx.x;
    float x = node[n * D + t];
    float s = x, sq = x * x;
    #pragma unroll
    for (int o = 32; o > 0; o >>= 1) {
        s  += __shfl_down(s, o);
        sq += __shfl_down(sq, o);
    }
    __shared__ float ss[4], sqs[4];
    if ((t & 63) == 0) { ss[t >> 6] = s; sqs[t >> 6] = sq; }
    __syncthreads();
    float S  = ss[0] + ss[1] + ss[2] + ss[3];
    float SQ = sqs[0] + sqs[1] + sqs[2] + sqs[3];
    float mu  = S * (1.f / D);
    float var = SQ * (1.f / D) - mu * mu;
    float inv = rsqrtf(var + LN_EPS);
    yb[n * D + t] = f2bf((x - mu) * inv * g[t] + b[t]);
}

// ---------------------------------------------------------------------------
// ALL weight transposes in one launch. z selects {Wk,Wv,Wq,Wg,Wback}.
// ---------------------------------------------------------------------------
__global__ __launch_bounds__(256)
void wtr_all(const float* __restrict__ Wk, const float* __restrict__ Wv,
             const float* __restrict__ Wq, const float* __restrict__ Wg,
             const float* __restrict__ Wback,
             u16* __restrict__ WT, u16* __restrict__ WT2, u16* __restrict__ WbT) {
    const int z = blockIdx.z;
    const float* W; u16* WTo; int K, Ncols;
    if      (z == 0) { W = Wk;    WTo = WT;                          K = D_SEQ; Ncols = HDH; }
    else if (z == 1) { W = Wv;    WTo = WT + (size_t)HDH * D_SEQ;    K = D_SEQ; Ncols = HDH; }
    else if (z == 2) { W = Wq;    WTo = WT2;                         K = D;     Ncols = HDH; }
    else if (z == 3) { W = Wg;    WTo = WT2 + (size_t)HDH * D;       K = D;     Ncols = HDH; }
    else             { W = Wback; WTo = WbT;                         K = HDH;   Ncols = D; }
    const int k0 = blockIdx.x * 32, n0 = blockIdx.y * 32;
    if (k0 >= K || n0 >= Ncols) return;
    __shared__ float tile[32][33];
    const int tx = threadIdx.x & 31, ty = threadIdx.x >> 5;
    #pragma unroll
    for (int i = 0; i < 32; i += 8)
        tile[ty + i][tx] = W[(size_t)(k0 + ty + i) * Ncols + n0 + tx];
    __syncthreads();
    #pragma unroll
    for (int i = 0; i < 32; i += 8)
        WTo[(size_t)(n0 + ty + i) * K + k0 + tx] = f2bf(tile[tx][ty + i]);
}

// ---------------------------------------------------------------------------
// zero exactly the pad regions of Kp and Qb (see round 10)
// ---------------------------------------------------------------------------
#define PAD_T 164864
__global__ __launch_bounds__(256)
void pad_kernel(u16* __restrict__ Kp, u16* __restrict__ Qb) {
    const int t = blockIdx.x * 256 + threadIdx.x;
    const int4 z = {0, 0, 0, 0};
    if (t < 131072) {
        const int row = t >> 1, half = t & 1;
        *(int4*)&Kp[(size_t)row * 64 + 48 + half * 8] = z;
    } else if (t < 164096) {
        const int u = t - 131072;
        const int row = u >> 1, half = u & 1;
        *(int4*)&Qb[(size_t)row * 64 + 48 + half * 8] = z;
    } else {
        const int u = t - 164096;
        const int row = u / 6, c = u - row * 6;      // row in [0,128)
        const int hh = row >> 4, m = 2048 + (row & 15);
        *(int4*)&Qb[((size_t)hh * QROWS + m) * 64 + c * 8] = z;
    }
}

// ---------------------------------------------------------------------------
// fused K|V projection v3: 64x128 tile (M x N), BK=64 -> 20 k-iterations
// (half the barrier drains of BK=32) at 768 blocks (3/CU co-residency).
// Per wave per iter: 16 MFMA. LDS 24 KB: As[kb0..7][64 rows][8],
// Bs[kb0..7][128 rows][8]; wave w stages kb chunks {w, w+4}.
// K -> Kp[b][h][s][64]; V -> V4[b][h][s/4][48][4].
// ---------------------------------------------------------------------------
__global__ __launch_bounds__(256)
void kv_gemm(const u16* __restrict__ A, const u16* __restrict__ WT,
             u16* __restrict__ Kp, u16* __restrict__ V4) {
    __shared__ __align__(16) u16 As[8 * 512];    // 8 KB
    __shared__ __align__(16) u16 Bs[8 * 1024];   // 16 KB
    const int tid = threadIdx.x;
    const int lane = tid & 63, wave = tid >> 6;
    const int glin = blockIdx.x;                 // 768
    const int xcd = glin & 7, rest = glin >> 3;  // rest < 96
    const int m0 = (xcd + 8 * (rest / 6)) * 64;  // 128 M-blocks of 64 rows
    const int n0 = (rest % 6) * 128;             // 6 N-blocks
    const int wm = (wave >> 1) * 32, wn = (wave & 1) * 64;
    const int lm = lane & 15, lq = lane >> 4;

    floatx4 acc[2][4] = {};

    // staging: wave w stages kb = w (k-off w*8) and kb = w+4 (k-off w*8+32)
    u16* asb0 = &As[wave * 512];
    u16* asb1 = &As[(wave + 4) * 512];
    u16* bsb0 = &Bs[wave * 1024];
    u16* bsb1 = &Bs[(wave + 4) * 1024];
    const u16* ag  = &A[(size_t)(m0 + lane) * D_SEQ + wave * 8];
    const u16* bg  = &WT[(size_t)(n0 + lane) * D_SEQ + wave * 8];
    const u16* bg2 = bg + (size_t)64 * D_SEQ;

    for (int k0 = 0; k0 < D_SEQ; k0 += 64) {
        __syncthreads();
        load_lds16(ag + k0, asb0);
        load_lds16(ag + k0 + 32, asb1);
        load_lds16(bg + k0, bsb0);
        load_lds16(bg + k0 + 32, bsb1);
        load_lds16(bg2 + k0, bsb0 + 512);
        load_lds16(bg2 + k0 + 32, bsb1 + 512);
        __syncthreads();

        #pragma unroll
        for (int kk = 0; kk < 2; ++kk) {
            const int kb = kk * 4 + lq;
            short8 af[2], bfr[4];
            #pragma unroll
            for (int i = 0; i < 2; ++i)
                af[i] = *(const short8*)&As[kb * 512 + (wm + i * 16 + lm) * 8];
            #pragma unroll
            for (int j = 0; j < 4; ++j)
                bfr[j] = *(const short8*)&Bs[kb * 1024 + (wn + j * 16 + lm) * 8];
            #pragma unroll
            for (int i = 0; i < 2; ++i)
                #pragma unroll
                for (int j = 0; j < 4; ++j)
                    acc[i][j] = __builtin_amdgcn_mfma_f32_16x16x32_bf16(
                        af[i], bfr[j], acc[i][j], 0, 0, 0);
        }
    }

    #pragma unroll
    for (int i = 0; i < 2; ++i) {
        const int mrow = m0 + wm + i * 16 + lq * 4;   // emb row = b*1024+s, s%4==0
        const int bb = mrow >> 10, s = mrow & 1023;
        #pragma unroll
        for (int j = 0; j < 4; ++j) {
            const int n = n0 + wn + j * 16 + lm;
            if (n < HDH) {
                const int hh = n / 48, dd = n - hh * 48;
                u16* kp = &Kp[(((size_t)(bb * N_HEAD + hh)) * S_LEN + s) * 64 + dd];
                kp[0]   = f2bf(acc[i][j][0]);
                kp[64]  = f2bf(acc[i][j][1]);
                kp[128] = f2bf(acc[i][j][2]);
                kp[192] = f2bf(acc[i][j][3]);
            } else {
                const int nv = n - HDH;
                const int hh = nv / 48, dd = nv - hh * 48;
                ushort4v pk;   // 4 consecutive s for fixed d
                pk[0] = f2bf(acc[i][j][0]); pk[1] = f2bf(acc[i][j][1]);
                pk[2] = f2bf(acc[i][j][2]); pk[3] = f2bf(acc[i][j][3]);
                *(ushort4v*)&V4[(((size_t)(bb * N_HEAD + hh)) * (S_LEN / 4) + (s >> 2)) * 192 + dd * 4] = pk;
            }
        }
    }
}

// ---------------------------------------------------------------------------
// fused Q|gate projection (unchanged)
// ---------------------------------------------------------------------------
__global__ __launch_bounds__(256)
void qg_gemm(const u16* __restrict__ Ab, const u16* __restrict__ WT2,
             const float* __restrict__ bg, u16* __restrict__ Qb,
             float* __restrict__ gate) {
    __shared__ __align__(16) u16 As[128 * 32];
    __shared__ __align__(16) u16 Bs[128 * 32];
    const int tid = threadIdx.x;
    const int lane = tid & 63, wave = tid >> 6;
    const int wm = (wave >> 1) * 64, wn = (wave & 1) * 64;
    const int m0 = blockIdx.y * 128, n0 = blockIdx.x * 128;
    const int lm = lane & 15, lq = lane >> 4;

    floatx4 acc[4][4] = {};
    const int sr = tid >> 2;
    const int sc = (tid & 3) * 8;

    for (int k0 = 0; k0 < D; k0 += 32) {
        const int4 a0 = *(const int4*)&Ab[(size_t)(m0 + sr) * D + k0 + sc];
        const int4 a1 = *(const int4*)&Ab[(size_t)(m0 + sr + 64) * D + k0 + sc];
        const int4 b0 = *(const int4*)&WT2[(size_t)(n0 + sr) * D + k0 + sc];
        const int4 b1 = *(const int4*)&WT2[(size_t)(n0 + sr + 64) * D + k0 + sc];
        __syncthreads();
        *(int4*)&As[sr * 32 + sc] = a0;
        *(int4*)&As[(sr + 64) * 32 + sc] = a1;
        *(int4*)&Bs[sr * 32 + sc] = b0;
        *(int4*)&Bs[(sr + 64) * 32 + sc] = b1;
        __syncthreads();

        short8 af[4], bfr[4];
        #pragma unroll
        for (int i = 0; i < 4; ++i)
            af[i] = *(const short8*)&As[(wm + i * 16 + lm) * 32 + lq * 8];
        #pragma unroll
        for (int i = 0; i < 4; ++i)
            bfr[i] = *(const short8*)&Bs[(wn + i * 16 + lm) * 32 + lq * 8];
        #pragma unroll
        for (int i = 0; i < 4; ++i)
            #pragma unroll
            for (int j = 0; j < 4; ++j)
                acc[i][j] = __builtin_amdgcn_mfma_f32_16x16x32_bf16(
                    af[i], bfr[j], acc[i][j], 0, 0, 0);
    }

    #pragma unroll
    for (int i = 0; i < 4; ++i) {
        const int mb = m0 + wm + i * 16 + lq * 4;
        #pragma unroll
        for (int j = 0; j < 4; ++j) {
            const int n = n0 + wn + j * 16 + lm;
            #pragma unroll
            for (int r = 0; r < 4; ++r) {
                const int m = mb + r;
                const float v = acc[i][j][r];
                if (n < HDH) {
                    const int hh = n / 48, dd = n - hh * 48;
                    Qb[((size_t)hh * QROWS + m) * 64 + dd] = f2bf(v * QSCALE);
                } else {
                    const int ng = n - HDH;
                    gate[(size_t)m * HDH + ng] = 1.f / (1.f + __expf(-(v + bg[ng])));
                }
            }
        }
    }
}

// ---------------------------------------------------------------------------
// back-projection (bf16 MFMA) — unchanged
// ---------------------------------------------------------------------------
__global__ __launch_bounds__(256)
void back_gemm(const u16* __restrict__ Ab, const u16* __restrict__ Bt,
               const float* __restrict__ bias, const float* __restrict__ resid,
               float* __restrict__ C) {
    __shared__ __align__(16) u16 As[128 * 32];
    __shared__ __align__(16) u16 Bs[128 * 32];
    const int tid = threadIdx.x;
    const int lane = tid & 63, wave = tid >> 6;
    const int wm = (wave >> 1) * 64, wn = (wave & 1) * 64;
    const int m0 = blockIdx.y * 128, n0 = blockIdx.x * 128;
    const int lm = lane & 15, lq = lane >> 4;

    floatx4 acc[4][4] = {};
    const int sr = tid >> 2;
    const int sc = (tid & 3) * 8;

    for (int k0 = 0; k0 < HDH; k0 += 32) {
        const int4 a0 = *(const int4*)&Ab[(size_t)(m0 + sr) * HDH + k0 + sc];
        const int4 a1 = *(const int4*)&Ab[(size_t)(m0 + sr + 64) * HDH + k0 + sc];
        const int4 b0 = *(const int4*)&Bt[(size_t)(n0 + sr) * HDH + k0 + sc];
        const int4 b1 = *(const int4*)&Bt[(size_t)(n0 + sr + 64) * HDH + k0 + sc];
        __syncthreads();
        *(int4*)&As[sr * 32 + sc] = a0;
        *(int4*)&As[(sr + 64) * 32 + sc] = a1;
        *(int4*)&Bs[sr * 32 + sc] = b0;
        *(int4*)&Bs[(sr + 64) * 32 + sc] = b1;
        __syncthreads();

        short8 af[4], bfr[4];
        #pragma unroll
        for (int i = 0; i < 4; ++i)
            af[i] = *(const short8*)&As[(wm + i * 16 + lm) * 32 + lq * 8];
        #pragma unroll
        for (int i = 0; i < 4; ++i)
            bfr[i] = *(const short8*)&Bs[(wn + i * 16 + lm) * 32 + lq * 8];
        #pragma unroll
        for (int i = 0; i < 4; ++i)
            #pragma unroll
            for (int j = 0; j < 4; ++j)
                acc[i][j] = __builtin_amdgcn_mfma_f32_16x16x32_bf16(
                    af[i], bfr[j], acc[i][j], 0, 0, 0);
    }

    #pragma unroll
    for (int i = 0; i < 4; ++i) {
        const int mb = m0 + wm + i * 16 + lq * 4;
        #pragma unroll
        for (int j = 0; j < 4; ++j) {
            const int n = n0 + wn + j * 16 + lm;
            #pragma unroll
            for (int r = 0; r < 4; ++r) {
                const int m = mb + r;
                C[(size_t)m * D + n] = acc[i][j][r] + bias[n] + resid[(size_t)m * D + n];
            }
        }
    }
}

// ---------------------------------------------------------------------------
// MFMA flash attention, S-split partials, coalesced V4 reads (unchanged)
// ---------------------------------------------------------------------------
__global__ __launch_bounds__(256)
void attn_mfma(const u16* __restrict__ Qb, const u16* __restrict__ Kp,
               const u16* __restrict__ V4, const int* __restrict__ mask,
               const int* __restrict__ ranges, const int* __restrict__ wl,
               float* __restrict__ Pacc, float* __restrict__ Pl) {
    const int e = wl[blockIdx.x];
    if (e < 0) return;
    const int b = e >> 16, n0 = e & 0xffff;
    const int h = blockIdx.y, sp = blockIdx.z;
    const int nend = ranges[b + 1];
    const int NT = min(16, nend - n0);

    const int tid = threadIdx.x;
    const int wave = tid >> 6, lane = tid & 63;
    const int lm = lane & 15, lq = lane >> 4;
    const int bh = b * N_HEAD + h;

    const u16* qrow = &Qb[((size_t)h * QROWS + n0 + lm) * 64];
    const short8 qf0 = *(const short8*)&qrow[lq * 8];
    const short8 qf1 = *(const short8*)&qrow[32 + lq * 8];

    const u16* kbase = &Kp[(size_t)bh * S_LEN * 64];
    const u16* vbase = &V4[(size_t)bh * (S_LEN / 4) * 192 + (size_t)lm * 4];
    const int* mrow = &mask[b * S_LEN];

    float l_i = 0.f;
    floatx4 acc0 = {}, acc1 = {}, acc2 = {};

    const int sbase = sp * 512 + wave * 128;
    const u16* kr0 = &kbase[(size_t)(sbase + lm) * 64];
    short8 nkf0 = *(const short8*)&kr0[lq * 8];
    short8 nkf1 = *(const short8*)&kr0[32 + lq * 8];
    int4 nmv = *(const int4*)&mrow[sbase + lq * 4];
    size_t vofs = (size_t)((sbase >> 2) + lq) * 192;
    short4v nvf0 = *(const short4v*)&vbase[vofs];
    short4v nvf1 = *(const short4v*)&vbase[vofs + 64];
    short4v nvf2 = *(const short4v*)&vbase[vofs + 128];

    for (int t = 0; t < 8; ++t) {
        const short8 kf0 = nkf0, kf1 = nkf1;
        const int4 mv = nmv;
        const short4v vf0 = nvf0, vf1 = nvf1, vf2 = nvf2;
        if (t < 7) {
            const int s1 = sbase + (t + 1) * 16;
            const u16* kr = &kbase[(size_t)(s1 + lm) * 64];
            nkf0 = *(const short8*)&kr[lq * 8];
            nkf1 = *(const short8*)&kr[32 + lq * 8];
            nmv = *(const int4*)&mrow[s1 + lq * 4];
            const size_t vo = (size_t)((s1 >> 2) + lq) * 192;
            nvf0 = *(const short4v*)&vbase[vo];
            nvf1 = *(const short4v*)&vbase[vo + 64];
            nvf2 = *(const short4v*)&vbase[vo + 128];
        }

        floatx4 st = {};
        st = __builtin_amdgcn_mfma_f32_16x16x32_bf16(kf0, qf0, st, 0, 0, 0);
        st = __builtin_amdgcn_mfma_f32_16x16x32_bf16(kf1, qf1, st, 0, 0, 0);

        const float p0 = mv.x > 0 ? exp2f(st[0]) : 0.f;
        const float p1 = mv.y > 0 ? exp2f(st[1]) : 0.f;
        const float p2 = mv.z > 0 ? exp2f(st[2]) : 0.f;
        const float p3 = mv.w > 0 ? exp2f(st[3]) : 0.f;
        l_i += (p0 + p1) + (p2 + p3);

        union { __hip_bfloat162 h2[2]; short4v v; } pu;
        pu.h2[0] = __float22bfloat162_rn(make_float2(p0, p1));
        pu.h2[1] = __float22bfloat162_rn(make_float2(p2, p3));

        acc0 = __builtin_amdgcn_mfma_f32_16x16x16bf16_1k(vf0, pu.v, acc0, 0, 0, 0);
        acc1 = __builtin_amdgcn_mfma_f32_16x16x16bf16_1k(vf1, pu.v, acc1, 0, 0, 0);
        acc2 = __builtin_amdgcn_mfma_f32_16x16x16bf16_1k(vf2, pu.v, acc2, 0, 0, 0);
    }

    l_i += __shfl_xor(l_i, 16);
    l_i += __shfl_xor(l_i, 32);

    __shared__ float sl[4][64];
    __shared__ float sacc[4][3][4][64];
    sl[wave][lane] = l_i;
    #pragma unroll
    for (int r = 0; r < 4; ++r) {
        sacc[wave][0][r][lane] = acc0[r];
        sacc[wave][1][r][lane] = acc1[r];
        sacc[wave][2][r][lane] = acc2[r];
    }
    __syncthreads();
    if (wave < 3 && lm < NT) {
        const int dt = wave;
        const float L = sl[0][lane] + sl[1][lane] + sl[2][lane] + sl[3][lane];
        const size_t o = (size_t)(n0 + lm) * HDH + h * 48 + dt * 16 + lq * 4;
        float4 ov;
        ov.x = sacc[0][dt][0][lane] + sacc[1][dt][0][lane] +
               sacc[2][dt][0][lane] + sacc[3][dt][0][lane];
        ov.y = sacc[0][dt][1][lane] + sacc[1][dt][1][lane] +
               sacc[2][dt][1][lane] + sacc[3][dt][1][lane];
        ov.z = sacc[0][dt][2][lane] + sacc[1][dt][2][lane] +
               sacc[2][dt][2][lane] + sacc[3][dt][2][lane];
        ov.w = sacc[0][dt][3][lane] + sacc[1][dt][3][lane] +
               sacc[2][dt][3][lane] + sacc[3][dt][3][lane];
        *(float4*)&Pacc[(size_t)sp * N_NODE * HDH + o] = ov;
        if (wave == 0 && lq == 0)
            Pl[(size_t)sp * N_NODE * N_HEAD + (n0 + lm) * N_HEAD + h] = L;
    }
}

// ---------------------------------------------------------------------------
// fuse: gfeatb = (P0+P1) / (L0+L1) * gate  -> bf16
// ---------------------------------------------------------------------------
__global__ __launch_bounds__(256)
void fuse_kernel(const float* __restrict__ Pacc, const float* __restrict__ Pl,
                 const float* __restrict__ gate, u16* __restrict__ gfeatb) {
    const size_t i4 = ((size_t)blockIdx.x * 256 + threadIdx.x) * 4;
    const int nh = (int)(i4 / 48);               // node*8 + h
    const float4 a = *(const float4*)&Pacc[i4];
    const float4 c = *(const float4*)&Pacc[(size_t)N_NODE * HDH + i4];
    const float4 g = *(const float4*)&gate[i4];
    const float L = Pl[nh] + Pl[N_NODE * N_HEAD + nh];
    const float inv = 1.f / (L + 1e-9f);
    union { __hip_bfloat162 h2[2]; ushort4v v; } r2;
    r2.h2[0] = __float22bfloat162_rn(make_float2((a.x + c.x) * inv * g.x,
                                                 (a.y + c.y) * inv * g.y));
    r2.h2[1] = __float22bfloat162_rn(make_float2((a.z + c.z) * inv * g.z,
                                                 (a.w + c.w) * inv * g.w));
    *(ushort4v*)&gfeatb[i4] = r2.v;
}

// ---------------------------------------------------------------------------
extern "C" void kernel_launch(void* const* d_in, const int* in_sizes, int n_in,
                              void* d_out, int out_size, void* d_ws, size_t ws_size,
                              hipStream_t stream) {
    const float* node  = (const float*)d_in[0];
    const float* emb   = (const float*)d_in[1];
    const int*   mask  = (const int*)d_in[2];
    const int*   batch = (const int*)d_in[3];
    const float* ln_g  = (const float*)d_in[4];
    const float* ln_b  = (const float*)d_in[5];
    const float* Wq    = (const float*)d_in[6];
    const float* Wk    = (const float*)d_in[7];
    const float* Wv    = (const float*)d_in[8];
    const float* Wg    = (const float*)d_in[9];
    const float* bg    = (const float*)d_in[10];
    const float* Wback = (const float*)d_in[11];
    const float* bback = (const float*)d_in[12];
    float* out = (float*)d_out;

    float* ws    = (float*)d_ws;
    float* gate  = ws;                                     // 2048*384 f32
    float* Pacc  = gate + (size_t)N_NODE * HDH;            // 2*2048*384 f32
    float* Pl    = Pacc + (size_t)2 * N_NODE * HDH;        // 2*2048*8 f32
    u16*   gfeatb = (u16*)(Pl + (size_t)2 * N_NODE * N_HEAD);  // 2048*384 u16
    u16*   yb    = gfeatb + (size_t)N_NODE * HDH;          // 2048*256 u16
    u16*   WT    = yb + (size_t)N_NODE * D;                // 768*1280 u16
    u16*   WT2   = WT + (size_t)KVN * D_SEQ;               // 768*256 u16
    u16*   WbT   = WT2 + (size_t)QGN * D;                  // 256*384 u16
    u16*   Qb    = WbT + (size_t)D * HDH;                  // 8*2064*64 u16
    u16*   Kp    = Qb + (size_t)N_HEAD * QROWS * 64;       // 64*1024*64 u16
    u16*   V4    = Kp + (size_t)B_GRAPH * N_HEAD * S_LEN * 64;  // 64*256*192 u16
    u16*   embb  = V4 + (size_t)B_GRAPH * N_HEAD * (S_LEN / 4) * 192; // 8192*1280
    int*   ranges = (int*)(embb + (size_t)B_GRAPH * S_LEN * D_SEQ);
    int*   wl    = ranges + 16;

    ranges_kernel<<<1, 64, 0, stream>>>(batch, ranges, wl);
    tobf16_kernel<<<(B_GRAPH * S_LEN * D_SEQ) / (256 * 8), 256, 0, stream>>>(emb, embb);
    ln_kernel<<<N_NODE, 256, 0, stream>>>(node, ln_g, ln_b, yb);
    wtr_all<<<dim3(D_SEQ / 32, HDH / 32, 5), 256, 0, stream>>>(
        Wk, Wv, Wq, Wg, Wback, WT, WT2, WbT);
    pad_kernel<<<PAD_T / 256, 256, 0, stream>>>(Kp, Qb);
    kv_gemm<<<768, 256, 0, stream>>>(embb, WT, Kp, V4);
    qg_gemm<<<dim3(QGN / 128, N_NODE / 128), 256, 0, stream>>>(
        yb, WT2, bg, Qb, gate);
    attn_mfma<<<dim3(NWL, N_HEAD, 2), 256, 0, stream>>>(
        Qb, Kp, V4, mask, ranges, wl, Pacc, Pl);
    fuse_kernel<<<(N_NODE * HDH) / (256 * 4), 256, 0, stream>>>(
        Pacc, Pl, gate, gfeatb);
    back_gemm<<<dim3(D / 128, N_NODE / 128), 256, 0, stream>>>(
        gfeatb, WbT, bback, node, out);
}

// Round 12
// 216.608 us; speedup vs baseline: 1.0888x; 1.0888x over previous
//
#include <hip/hip_runtime.h>
#include <hip/hip_bf16.h>
#include <math.h>

#define D 256
#define D_SEQ 1280
#define D_HEAD 48
#define N_HEAD 8
#define HDH 384        // N_HEAD * D_HEAD
#define N_NODE 2048
#define B_GRAPH 8
#define S_LEN 1024
#define LN_EPS 1e-5f
#define QSCALE (0.14433756729740643f * 1.4426950408889634f)  // 1/sqrt(48)*log2(e)
#define KVN 768        // fused K|V gemm output width
#define QGN 768        // fused Q|gate gemm output width
#define QROWS (N_NODE + 16)              // padded Q rows per head
#define TPG 40         // max 16-node tiles per graph
#define NWL (TPG * 8)  // strided worklist: wl[i*8+b]

typedef unsigned short u16;
typedef __attribute__((ext_vector_type(8))) short short8;
typedef __attribute__((ext_vector_type(4))) short short4v;
typedef __attribute__((ext_vector_type(4))) unsigned short ushort4v;
typedef __attribute__((ext_vector_type(4))) float floatx4;

__device__ __forceinline__ u16 f2bf(float f) {
    unsigned int x = __float_as_uint(f);
    x += 0x7fff + ((x >> 16) & 1);      // RNE to bf16
    return (u16)(x >> 16);
}

// async 16B-per-lane global->LDS DMA (wave-uniform LDS base + lane*16B)
__device__ __forceinline__ void load_lds16(const u16* g, u16* lds) {
    __builtin_amdgcn_global_load_lds(
        (const __attribute__((address_space(1))) unsigned int*)g,
        (__attribute__((address_space(3))) unsigned int*)lds, 16, 0, 0);
}

// ---------------------------------------------------------------------------
// ranges + graph-strided worklist: wl[i*8+b] = (b<<16)|n0, -1 if i >= ntiles(b).
// ---------------------------------------------------------------------------
__global__ void ranges_kernel(const int* __restrict__ batch, int* __restrict__ ranges,
                              int* __restrict__ wl) {
    int t = threadIdx.x;
    if (t <= B_GRAPH) {
        int lo = 0, hi = N_NODE;
        while (lo < hi) {
            int mid = (lo + hi) >> 1;
            if (batch[mid] < t) lo = mid + 1; else hi = mid;
        }
        ranges[t] = lo;
    }
    __syncthreads();
    if (t < B_GRAPH) {
        const int s = ranges[t];
        const int ntile = (ranges[t + 1] - s + 15) >> 4;
        for (int i = 0; i < TPG; ++i)
            wl[i * 8 + t] = (i < ntile) ? ((t << 16) | (s + i * 16)) : -1;
    }
}

// ---------------------------------------------------------------------------
__global__ __launch_bounds__(256)
void tobf16_kernel(const float* __restrict__ in, u16* __restrict__ out) {
    const size_t i = ((size_t)blockIdx.x * 256 + threadIdx.x) * 8;
    const float4 a = *(const float4*)&in[i];
    const float4 b = *(const float4*)&in[i + 4];
    union { u16 u[8]; int4 v; } p;
    p.u[0]=f2bf(a.x); p.u[1]=f2bf(a.y); p.u[2]=f2bf(a.z); p.u[3]=f2bf(a.w);
    p.u[4]=f2bf(b.x); p.u[5]=f2bf(b.y); p.u[6]=f2bf(b.z); p.u[7]=f2bf(b.w);
    *(int4*)&out[i] = p.v;
}

// ---------------------------------------------------------------------------
__global__ __launch_bounds__(256)
void ln_kernel(const float* __restrict__ node, const float* __restrict__ g,
               const float* __restrict__ b, u16* __restrict__ yb) {
    int n = blockIdx.x, t = threadIdx.x;
    float x = node[n * D + t];
    float s = x, sq = x * x;
    #pragma unroll
    for (int o = 32; o > 0; o >>= 1) {
        s  += __shfl_down(s, o);
        sq += __shfl_down(sq, o);
    }
    __shared__ float ss[4], sqs[4];
    if ((t & 63) == 0) { ss[t >> 6] = s; sqs[t >> 6] = sq; }
    __syncthreads();
    float S  = ss[0] + ss[1] + ss[2] + ss[3];
    float SQ = sqs[0] + sqs[1] + sqs[2] + sqs[3];
    float mu  = S * (1.f / D);
    float var = SQ * (1.f / D) - mu * mu;
    float inv = rsqrtf(var + LN_EPS);
    yb[n * D + t] = f2bf((x - mu) * inv * g[t] + b[t]);
}

// ---------------------------------------------------------------------------
// ALL weight transposes in one launch. z selects {Wk,Wv,Wq,Wg,Wback}.
// ---------------------------------------------------------------------------
__global__ __launch_bounds__(256)
void wtr_all(const float* __restrict__ Wk, const float* __restrict__ Wv,
             const float* __restrict__ Wq, const float* __restrict__ Wg,
             const float* __restrict__ Wback,
             u16* __restrict__ WT, u16* __restrict__ WT2, u16* __restrict__ WbT) {
    const int z = blockIdx.z;
    const float* W; u16* WTo; int K, Ncols;
    if      (z == 0) { W = Wk;    WTo = WT;                          K = D_SEQ; Ncols = HDH; }
    else if (z == 1) { W = Wv;    WTo = WT + (size_t)HDH * D_SEQ;    K = D_SEQ; Ncols = HDH; }
    else if (z == 2) { W = Wq;    WTo = WT2;                         K = D;     Ncols = HDH; }
    else if (z == 3) { W = Wg;    WTo = WT2 + (size_t)HDH * D;       K = D;     Ncols = HDH; }
    else             { W = Wback; WTo = WbT;                         K = HDH;   Ncols = D; }
    const int k0 = blockIdx.x * 32, n0 = blockIdx.y * 32;
    if (k0 >= K || n0 >= Ncols) return;
    __shared__ float tile[32][33];
    const int tx = threadIdx.x & 31, ty = threadIdx.x >> 5;
    #pragma unroll
    for (int i = 0; i < 32; i += 8)
        tile[ty + i][tx] = W[(size_t)(k0 + ty + i) * Ncols + n0 + tx];
    __syncthreads();
    #pragma unroll
    for (int i = 0; i < 32; i += 8)
        WTo[(size_t)(n0 + ty + i) * K + k0 + tx] = f2bf(tile[tx][ty + i]);
}

// ---------------------------------------------------------------------------
// zero exactly the pad regions of Kp and Qb (see round 10)
// ---------------------------------------------------------------------------
#define PAD_T 164864
__global__ __launch_bounds__(256)
void pad_kernel(u16* __restrict__ Kp, u16* __restrict__ Qb) {
    const int t = blockIdx.x * 256 + threadIdx.x;
    const int4 z = {0, 0, 0, 0};
    if (t < 131072) {
        const int row = t >> 1, half = t & 1;
        *(int4*)&Kp[(size_t)row * 64 + 48 + half * 8] = z;
    } else if (t < 164096) {
        const int u = t - 131072;
        const int row = u >> 1, half = u & 1;
        *(int4*)&Qb[(size_t)row * 64 + 48 + half * 8] = z;
    } else {
        const int u = t - 164096;
        const int row = u / 6, c = u - row * 6;      // row in [0,128)
        const int hh = row >> 4, m = 2048 + (row & 15);
        *(int4*)&Qb[((size_t)hh * QROWS + m) * 64 + c * 8] = z;
    }
}

// ---------------------------------------------------------------------------
// fused K|V projection v4: 64x128 tile, BK=32, m97-COALESCED staging.
// LDS row-major [row][32] (A 4KB, B 8KB): each 1KB DMA maps 4 lanes per
// matrix row (16B each, 64B/row contiguous) -> 16 cache lines per DMA
// (vs 64 with one-lane-per-row). Fragment ds_read_b128 at 64B row stride
// (2-way-aliased banks, m97-style - LDS is not the bottleneck).
// 768 blocks (3/CU), XCD swizzle. K -> Kp[b][h][s][64]; V -> V4[..][48][4].
// ---------------------------------------------------------------------------
__global__ __launch_bounds__(256)
void kv_gemm(const u16* __restrict__ A, const u16* __restrict__ WT,
             u16* __restrict__ Kp, u16* __restrict__ V4) {
    __shared__ __align__(16) u16 As[64 * 32];    // 4 KB  [row][k]
    __shared__ __align__(16) u16 Bs[128 * 32];   // 8 KB  [row][k]
    const int tid = threadIdx.x;
    const int lane = tid & 63, wave = tid >> 6;
    const int glin = blockIdx.x;                 // 768
    const int xcd = glin & 7, rest = glin >> 3;  // rest < 96
    const int m0 = (xcd + 8 * (rest / 6)) * 64;  // 128 M-blocks of 64 rows
    const int n0 = (rest % 6) * 128;             // 6 N-blocks
    const int wm = (wave >> 1) * 32, wn = (wave & 1) * 64;
    const int lm = lane & 15, lq = lane >> 4;

    floatx4 acc[2][4] = {};

    // coalesced staging: wave w covers rows w*16 + lane/4, col (lane&3)*8.
    // LDS dst (wave-uniform): row block w*16 -> u16 offset w*512.
    const int srow = lane >> 2, scol = (lane & 3) * 8;
    const u16* ag  = &A[(size_t)(m0 + wave * 16 + srow) * D_SEQ + scol];
    const u16* bg  = &WT[(size_t)(n0 + wave * 16 + srow) * D_SEQ + scol];
    const u16* bg2 = bg + (size_t)64 * D_SEQ;
    u16* asb = &As[wave * 512];
    u16* bsb = &Bs[wave * 512];
    u16* bsb2 = &Bs[2048 + wave * 512];

    for (int k0 = 0; k0 < D_SEQ; k0 += 32) {
        __syncthreads();
        load_lds16(ag + k0, asb);
        load_lds16(bg + k0, bsb);
        load_lds16(bg2 + k0, bsb2);
        __syncthreads();

        short8 af[2], bfr[4];
        #pragma unroll
        for (int i = 0; i < 2; ++i)
            af[i] = *(const short8*)&As[(wm + i * 16 + lm) * 32 + lq * 8];
        #pragma unroll
        for (int j = 0; j < 4; ++j)
            bfr[j] = *(const short8*)&Bs[(wn + j * 16 + lm) * 32 + lq * 8];
        #pragma unroll
        for (int i = 0; i < 2; ++i)
            #pragma unroll
            for (int j = 0; j < 4; ++j)
                acc[i][j] = __builtin_amdgcn_mfma_f32_16x16x32_bf16(
                    af[i], bfr[j], acc[i][j], 0, 0, 0);
    }

    #pragma unroll
    for (int i = 0; i < 2; ++i) {
        const int mrow = m0 + wm + i * 16 + lq * 4;   // emb row = b*1024+s, s%4==0
        const int bb = mrow >> 10, s = mrow & 1023;
        #pragma unroll
        for (int j = 0; j < 4; ++j) {
            const int n = n0 + wn + j * 16 + lm;
            if (n < HDH) {
                const int hh = n / 48, dd = n - hh * 48;
                u16* kp = &Kp[(((size_t)(bb * N_HEAD + hh)) * S_LEN + s) * 64 + dd];
                kp[0]   = f2bf(acc[i][j][0]);
                kp[64]  = f2bf(acc[i][j][1]);
                kp[128] = f2bf(acc[i][j][2]);
                kp[192] = f2bf(acc[i][j][3]);
            } else {
                const int nv = n - HDH;
                const int hh = nv / 48, dd = nv - hh * 48;
                ushort4v pk;   // 4 consecutive s for fixed d
                pk[0] = f2bf(acc[i][j][0]); pk[1] = f2bf(acc[i][j][1]);
                pk[2] = f2bf(acc[i][j][2]); pk[3] = f2bf(acc[i][j][3]);
                *(ushort4v*)&V4[(((size_t)(bb * N_HEAD + hh)) * (S_LEN / 4) + (s >> 2)) * 192 + dd * 4] = pk;
            }
        }
    }
}

// ---------------------------------------------------------------------------
// fused Q|gate projection (unchanged)
// ---------------------------------------------------------------------------
__global__ __launch_bounds__(256)
void qg_gemm(const u16* __restrict__ Ab, const u16* __restrict__ WT2,
             const float* __restrict__ bg, u16* __restrict__ Qb,
             float* __restrict__ gate) {
    __shared__ __align__(16) u16 As[128 * 32];
    __shared__ __align__(16) u16 Bs[128 * 32];
    const int tid = threadIdx.x;
    const int lane = tid & 63, wave = tid >> 6;
    const int wm = (wave >> 1) * 64, wn = (wave & 1) * 64;
    const int m0 = blockIdx.y * 128, n0 = blockIdx.x * 128;
    const int lm = lane & 15, lq = lane >> 4;

    floatx4 acc[4][4] = {};
    const int sr = tid >> 2;
    const int sc = (tid & 3) * 8;

    for (int k0 = 0; k0 < D; k0 += 32) {
        const int4 a0 = *(const int4*)&Ab[(size_t)(m0 + sr) * D + k0 + sc];
        const int4 a1 = *(const int4*)&Ab[(size_t)(m0 + sr + 64) * D + k0 + sc];
        const int4 b0 = *(const int4*)&WT2[(size_t)(n0 + sr) * D + k0 + sc];
        const int4 b1 = *(const int4*)&WT2[(size_t)(n0 + sr + 64) * D + k0 + sc];
        __syncthreads();
        *(int4*)&As[sr * 32 + sc] = a0;
        *(int4*)&As[(sr + 64) * 32 + sc] = a1;
        *(int4*)&Bs[sr * 32 + sc] = b0;
        *(int4*)&Bs[(sr + 64) * 32 + sc] = b1;
        __syncthreads();

        short8 af[4], bfr[4];
        #pragma unroll
        for (int i = 0; i < 4; ++i)
            af[i] = *(const short8*)&As[(wm + i * 16 + lm) * 32 + lq * 8];
        #pragma unroll
        for (int i = 0; i < 4; ++i)
            bfr[i] = *(const short8*)&Bs[(wn + i * 16 + lm) * 32 + lq * 8];
        #pragma unroll
        for (int i = 0; i < 4; ++i)
            #pragma unroll
            for (int j = 0; j < 4; ++j)
                acc[i][j] = __builtin_amdgcn_mfma_f32_16x16x32_bf16(
                    af[i], bfr[j], acc[i][j], 0, 0, 0);
    }

    #pragma unroll
    for (int i = 0; i < 4; ++i) {
        const int mb = m0 + wm + i * 16 + lq * 4;
        #pragma unroll
        for (int j = 0; j < 4; ++j) {
            const int n = n0 + wn + j * 16 + lm;
            #pragma unroll
            for (int r = 0; r < 4; ++r) {
                const int m = mb + r;
                const float v = acc[i][j][r];
                if (n < HDH) {
                    const int hh = n / 48, dd = n - hh * 48;
                    Qb[((size_t)hh * QROWS + m) * 64 + dd] = f2bf(v * QSCALE);
                } else {
                    const int ng = n - HDH;
                    gate[(size_t)m * HDH + ng] = 1.f / (1.f + __expf(-(v + bg[ng])));
                }
            }
        }
    }
}

// ---------------------------------------------------------------------------
// back-projection (bf16 MFMA) — unchanged
// ---------------------------------------------------------------------------
__global__ __launch_bounds__(256)
void back_gemm(const u16* __restrict__ Ab, const u16* __restrict__ Bt,
               const float* __restrict__ bias, const float* __restrict__ resid,
               float* __restrict__ C) {
    __shared__ __align__(16) u16 As[128 * 32];
    __shared__ __align__(16) u16 Bs[128 * 32];
    const int tid = threadIdx.x;
    const int lane = tid & 63, wave = tid >> 6;
    const int wm = (wave >> 1) * 64, wn = (wave & 1) * 64;
    const int m0 = blockIdx.y * 128, n0 = blockIdx.x * 128;
    const int lm = lane & 15, lq = lane >> 4;

    floatx4 acc[4][4] = {};
    const int sr = tid >> 2;
    const int sc = (tid & 3) * 8;

    for (int k0 = 0; k0 < HDH; k0 += 32) {
        const int4 a0 = *(const int4*)&Ab[(size_t)(m0 + sr) * HDH + k0 + sc];
        const int4 a1 = *(const int4*)&Ab[(size_t)(m0 + sr + 64) * HDH + k0 + sc];
        const int4 b0 = *(const int4*)&Bt[(size_t)(n0 + sr) * HDH + k0 + sc];
        const int4 b1 = *(const int4*)&Bt[(size_t)(n0 + sr + 64) * HDH + k0 + sc];
        __syncthreads();
        *(int4*)&As[sr * 32 + sc] = a0;
        *(int4*)&As[(sr + 64) * 32 + sc] = a1;
        *(int4*)&Bs[sr * 32 + sc] = b0;
        *(int4*)&Bs[(sr + 64) * 32 + sc] = b1;
        __syncthreads();

        short8 af[4], bfr[4];
        #pragma unroll
        for (int i = 0; i < 4; ++i)
            af[i] = *(const short8*)&As[(wm + i * 16 + lm) * 32 + lq * 8];
        #pragma unroll
        for (int i = 0; i < 4; ++i)
            bfr[i] = *(const short8*)&Bs[(wn + i * 16 + lm) * 32 + lq * 8];
        #pragma unroll
        for (int i = 0; i < 4; ++i)
            #pragma unroll
            for (int j = 0; j < 4; ++j)
                acc[i][j] = __builtin_amdgcn_mfma_f32_16x16x32_bf16(
                    af[i], bfr[j], acc[i][j], 0, 0, 0);
    }

    #pragma unroll
    for (int i = 0; i < 4; ++i) {
        const int mb = m0 + wm + i * 16 + lq * 4;
        #pragma unroll
        for (int j = 0; j < 4; ++j) {
            const int n = n0 + wn + j * 16 + lm;
            #pragma unroll
            for (int r = 0; r < 4; ++r) {
                const int m = mb + r;
                C[(size_t)m * D + n] = acc[i][j][r] + bias[n] + resid[(size_t)m * D + n];
            }
        }
    }
}

// ---------------------------------------------------------------------------
// MFMA flash attention, S-split partials, coalesced V4 reads (unchanged)
// ---------------------------------------------------------------------------
__global__ __launch_bounds__(256)
void attn_mfma(const u16* __restrict__ Qb, const u16* __restrict__ Kp,
               const u16* __restrict__ V4, const int* __restrict__ mask,
               const int* __restrict__ ranges, const int* __restrict__ wl,
               float* __restrict__ Pacc, float* __restrict__ Pl) {
    const int e = wl[blockIdx.x];
    if (e < 0) return;
    const int b = e >> 16, n0 = e & 0xffff;
    const int h = blockIdx.y, sp = blockIdx.z;
    const int nend = ranges[b + 1];
    const int NT = min(16, nend - n0);

    const int tid = threadIdx.x;
    const int wave = tid >> 6, lane = tid & 63;
    const int lm = lane & 15, lq = lane >> 4;
    const int bh = b * N_HEAD + h;

    const u16* qrow = &Qb[((size_t)h * QROWS + n0 + lm) * 64];
    const short8 qf0 = *(const short8*)&qrow[lq * 8];
    const short8 qf1 = *(const short8*)&qrow[32 + lq * 8];

    const u16* kbase = &Kp[(size_t)bh * S_LEN * 64];
    const u16* vbase = &V4[(size_t)bh * (S_LEN / 4) * 192 + (size_t)lm * 4];
    const int* mrow = &mask[b * S_LEN];

    float l_i = 0.f;
    floatx4 acc0 = {}, acc1 = {}, acc2 = {};

    const int sbase = sp * 512 + wave * 128;
    const u16* kr0 = &kbase[(size_t)(sbase + lm) * 64];
    short8 nkf0 = *(const short8*)&kr0[lq * 8];
    short8 nkf1 = *(const short8*)&kr0[32 + lq * 8];
    int4 nmv = *(const int4*)&mrow[sbase + lq * 4];
    size_t vofs = (size_t)((sbase >> 2) + lq) * 192;
    short4v nvf0 = *(const short4v*)&vbase[vofs];
    short4v nvf1 = *(const short4v*)&vbase[vofs + 64];
    short4v nvf2 = *(const short4v*)&vbase[vofs + 128];

    for (int t = 0; t < 8; ++t) {
        const short8 kf0 = nkf0, kf1 = nkf1;
        const int4 mv = nmv;
        const short4v vf0 = nvf0, vf1 = nvf1, vf2 = nvf2;
        if (t < 7) {
            const int s1 = sbase + (t + 1) * 16;
            const u16* kr = &kbase[(size_t)(s1 + lm) * 64];
            nkf0 = *(const short8*)&kr[lq * 8];
            nkf1 = *(const short8*)&kr[32 + lq * 8];
            nmv = *(const int4*)&mrow[s1 + lq * 4];
            const size_t vo = (size_t)((s1 >> 2) + lq) * 192;
            nvf0 = *(const short4v*)&vbase[vo];
            nvf1 = *(const short4v*)&vbase[vo + 64];
            nvf2 = *(const short4v*)&vbase[vo + 128];
        }

        floatx4 st = {};
        st = __builtin_amdgcn_mfma_f32_16x16x32_bf16(kf0, qf0, st, 0, 0, 0);
        st = __builtin_amdgcn_mfma_f32_16x16x32_bf16(kf1, qf1, st, 0, 0, 0);

        const float p0 = mv.x > 0 ? exp2f(st[0]) : 0.f;
        const float p1 = mv.y > 0 ? exp2f(st[1]) : 0.f;
        const float p2 = mv.z > 0 ? exp2f(st[2]) : 0.f;
        const float p3 = mv.w > 0 ? exp2f(st[3]) : 0.f;
        l_i += (p0 + p1) + (p2 + p3);

        union { __hip_bfloat162 h2[2]; short4v v; } pu;
        pu.h2[0] = __float22bfloat162_rn(make_float2(p0, p1));
        pu.h2[1] = __float22bfloat162_rn(make_float2(p2, p3));

        acc0 = __builtin_amdgcn_mfma_f32_16x16x16bf16_1k(vf0, pu.v, acc0, 0, 0, 0);
        acc1 = __builtin_amdgcn_mfma_f32_16x16x16bf16_1k(vf1, pu.v, acc1, 0, 0, 0);
        acc2 = __builtin_amdgcn_mfma_f32_16x16x16bf16_1k(vf2, pu.v, acc2, 0, 0, 0);
    }

    l_i += __shfl_xor(l_i, 16);
    l_i += __shfl_xor(l_i, 32);

    __shared__ float sl[4][64];
    __shared__ float sacc[4][3][4][64];
    sl[wave][lane] = l_i;
    #pragma unroll
    for (int r = 0; r < 4; ++r) {
        sacc[wave][0][r][lane] = acc0[r];
        sacc[wave][1][r][lane] = acc1[r];
        sacc[wave][2][r][lane] = acc2[r];
    }
    __syncthreads();
    if (wave < 3 && lm < NT) {
        const int dt = wave;
        const float L = sl[0][lane] + sl[1][lane] + sl[2][lane] + sl[3][lane];
        const size_t o = (size_t)(n0 + lm) * HDH + h * 48 + dt * 16 + lq * 4;
        float4 ov;
        ov.x = sacc[0][dt][0][lane] + sacc[1][dt][0][lane] +
               sacc[2][dt][0][lane] + sacc[3][dt][0][lane];
        ov.y = sacc[0][dt][1][lane] + sacc[1][dt][1][lane] +
               sacc[2][dt][1][lane] + sacc[3][dt][1][lane];
        ov.z = sacc[0][dt][2][lane] + sacc[1][dt][2][lane] +
               sacc[2][dt][2][lane] + sacc[3][dt][2][lane];
        ov.w = sacc[0][dt][3][lane] + sacc[1][dt][3][lane] +
               sacc[2][dt][3][lane] + sacc[3][dt][3][lane];
        *(float4*)&Pacc[(size_t)sp * N_NODE * HDH + o] = ov;
        if (wave == 0 && lq == 0)
            Pl[(size_t)sp * N_NODE * N_HEAD + (n0 + lm) * N_HEAD + h] = L;
    }
}

// ---------------------------------------------------------------------------
// fuse: gfeatb = (P0+P1) / (L0+L1) * gate  -> bf16
// ---------------------------------------------------------------------------
__global__ __launch_bounds__(256)
void fuse_kernel(const float* __restrict__ Pacc, const float* __restrict__ Pl,
                 const float* __restrict__ gate, u16* __restrict__ gfeatb) {
    const size_t i4 = ((size_t)blockIdx.x * 256 + threadIdx.x) * 4;
    const int nh = (int)(i4 / 48);               // node*8 + h
    const float4 a = *(const float4*)&Pacc[i4];
    const float4 c = *(const float4*)&Pacc[(size_t)N_NODE * HDH + i4];
    const float4 g = *(const float4*)&gate[i4];
    const float L = Pl[nh] + Pl[N_NODE * N_HEAD + nh];
    const float inv = 1.f / (L + 1e-9f);
    union { __hip_bfloat162 h2[2]; ushort4v v; } r2;
    r2.h2[0] = __float22bfloat162_rn(make_float2((a.x + c.x) * inv * g.x,
                                                 (a.y + c.y) * inv * g.y));
    r2.h2[1] = __float22bfloat162_rn(make_float2((a.z + c.z) * inv * g.z,
                                                 (a.w + c.w) * inv * g.w));
    *(ushort4v*)&gfeatb[i4] = r2.v;
}

// ---------------------------------------------------------------------------
extern "C" void kernel_launch(void* const* d_in, const int* in_sizes, int n_in,
                              void* d_out, int out_size, void* d_ws, size_t ws_size,
                              hipStream_t stream) {
    const float* node  = (const float*)d_in[0];
    const float* emb   = (const float*)d_in[1];
    const int*   mask  = (const int*)d_in[2];
    const int*   batch = (const int*)d_in[3];
    const float* ln_g  = (const float*)d_in[4];
    const float* ln_b  = (const float*)d_in[5];
    const float* Wq    = (const float*)d_in[6];
    const float* Wk    = (const float*)d_in[7];
    const float* Wv    = (const float*)d_in[8];
    const float* Wg    = (const float*)d_in[9];
    const float* bg    = (const float*)d_in[10];
    const float* Wback = (const float*)d_in[11];
    const float* bback = (const float*)d_in[12];
    float* out = (float*)d_out;

    float* ws    = (float*)d_ws;
    float* gate  = ws;                                     // 2048*384 f32
    float* Pacc  = gate + (size_t)N_NODE * HDH;            // 2*2048*384 f32
    float* Pl    = Pacc + (size_t)2 * N_NODE * HDH;        // 2*2048*8 f32
    u16*   gfeatb = (u16*)(Pl + (size_t)2 * N_NODE * N_HEAD);  // 2048*384 u16
    u16*   yb    = gfeatb + (size_t)N_NODE * HDH;          // 2048*256 u16
    u16*   WT    = yb + (size_t)N_NODE * D;                // 768*1280 u16
    u16*   WT2   = WT + (size_t)KVN * D_SEQ;               // 768*256 u16
    u16*   WbT   = WT2 + (size_t)QGN * D;                  // 256*384 u16
    u16*   Qb    = WbT + (size_t)D * HDH;                  // 8*2064*64 u16
    u16*   Kp    = Qb + (size_t)N_HEAD * QROWS * 64;       // 64*1024*64 u16
    u16*   V4    = Kp + (size_t)B_GRAPH * N_HEAD * S_LEN * 64;  // 64*256*192 u16
    u16*   embb  = V4 + (size_t)B_GRAPH * N_HEAD * (S_LEN / 4) * 192; // 8192*1280
    int*   ranges = (int*)(embb + (size_t)B_GRAPH * S_LEN * D_SEQ);
    int*   wl    = ranges + 16;

    ranges_kernel<<<1, 64, 0, stream>>>(batch, ranges, wl);
    tobf16_kernel<<<(B_GRAPH * S_LEN * D_SEQ) / (256 * 8), 256, 0, stream>>>(emb, embb);
    ln_kernel<<<N_NODE, 256, 0, stream>>>(node, ln_g, ln_b, yb);
    wtr_all<<<dim3(D_SEQ / 32, HDH / 32, 5), 256, 0, stream>>>(
        Wk, Wv, Wq, Wg, Wback, WT, WT2, WbT);
    pad_kernel<<<PAD_T / 256, 256, 0, stream>>>(Kp, Qb);
    kv_gemm<<<768, 256, 0, stream>>>(embb, WT, Kp, V4);
    qg_gemm<<<dim3(QGN / 128, N_NODE / 128), 256, 0, stream>>>(
        yb, WT2, bg, Qb, gate);
    attn_mfma<<<dim3(NWL, N_HEAD, 2), 256, 0, stream>>>(
        Qb, Kp, V4, mask, ranges, wl, Pacc, Pl);
    fuse_kernel<<<(N_NODE * HDH) / (256 * 4), 256, 0, stream>>>(
        Pacc, Pl, gate, gfeatb);
    back_gemm<<<dim3(D / 128, N_NODE / 128), 256, 0, stream>>>(
        gfeatb, WbT, bback, node, out);
}

// Round 13
// 209.543 us; speedup vs baseline: 1.1255x; 1.0337x over previous
//
#include <hip/hip_runtime.h>
#include <hip/hip_bf16.h>
#include <math.h>

#define D 256
#define D_SEQ 1280
#define D_HEAD 48
#define N_HEAD 8
#define HDH 384        // N_HEAD * D_HEAD
#define N_NODE 2048
#define B_GRAPH 8
#define S_LEN 1024
#define LN_EPS 1e-5f
#define QSCALE (0.14433756729740643f * 1.4426950408889634f)  // 1/sqrt(48)*log2(e)
#define KVN 768        // fused K|V gemm output width
#define QGN 768        // fused Q|gate gemm output width
#define QROWS (N_NODE + 16)              // padded Q rows per head
#define TPG 40         // max 16-node tiles per graph
#define NWL (TPG * 8)  // strided worklist: wl[i*8+b]

typedef unsigned short u16;
typedef __attribute__((ext_vector_type(8))) short short8;
typedef __attribute__((ext_vector_type(4))) short short4v;
typedef __attribute__((ext_vector_type(4))) unsigned short ushort4v;
typedef __attribute__((ext_vector_type(4))) float floatx4;

__device__ __forceinline__ u16 f2bf(float f) {
    unsigned int x = __float_as_uint(f);
    x += 0x7fff + ((x >> 16) & 1);      // RNE to bf16
    return (u16)(x >> 16);
}

// async 16B-per-lane global->LDS DMA (wave-uniform LDS base + lane*16B)
__device__ __forceinline__ void load_lds16(const u16* g, u16* lds) {
    __builtin_amdgcn_global_load_lds(
        (const __attribute__((address_space(1))) unsigned int*)g,
        (__attribute__((address_space(3))) unsigned int*)lds, 16, 0, 0);
}

// ---------------------------------------------------------------------------
// prep_small: block 0 = ranges + worklist; blocks 1.. = pad zeroing.
// pad regions: Kp cols 48..63 (all 65536 rows), Qb cols 48..63 (8*2064 rows),
// Qb pad rows 2048..2063 cols 0..47.
// ---------------------------------------------------------------------------
#define PAD_T 164864
__global__ void prep_small(const int* __restrict__ batch, int* __restrict__ ranges,
                           int* __restrict__ wl, u16* __restrict__ Kp,
                           u16* __restrict__ Qb) {
    if (blockIdx.x == 0) {
        int t = threadIdx.x;
        if (t <= B_GRAPH) {
            int lo = 0, hi = N_NODE;
            while (lo < hi) {
                int mid = (lo + hi) >> 1;
                if (batch[mid] < t) lo = mid + 1; else hi = mid;
            }
            ranges[t] = lo;
        }
        __syncthreads();
        if (t < B_GRAPH) {
            const int s = ranges[t];
            const int ntile = (ranges[t + 1] - s + 15) >> 4;
            for (int i = 0; i < TPG; ++i)
                wl[i * 8 + t] = (i < ntile) ? ((t << 16) | (s + i * 16)) : -1;
        }
        return;
    }
    const int t = (blockIdx.x - 1) * 256 + threadIdx.x;
    if (t >= PAD_T) return;
    const int4 z = {0, 0, 0, 0};
    if (t < 131072) {
        const int row = t >> 1, half = t & 1;
        *(int4*)&Kp[(size_t)row * 64 + 48 + half * 8] = z;
    } else if (t < 164096) {
        const int u = t - 131072;
        const int row = u >> 1, half = u & 1;
        *(int4*)&Qb[(size_t)row * 64 + 48 + half * 8] = z;
    } else {
        const int u = t - 164096;
        const int row = u / 6, c = u - row * 6;      // row in [0,128)
        const int hh = row >> 4, m = 2048 + (row & 15);
        *(int4*)&Qb[((size_t)hh * QROWS + m) * 64 + c * 8] = z;
    }
}

// ---------------------------------------------------------------------------
// prep_big: sectioned 1-D grid.
//   [0, 5120)          : emb fp32 -> bf16 (2048 elems/block)
//   [5120, 7168)       : layernorm -> bf16 (1 node/block)
//   [7168, 8416)       : weight transposes (Wk 480 | Wv 480 | Wq 96 | Wg 96 | Wback 96)
// ---------------------------------------------------------------------------
__global__ __launch_bounds__(256)
void prep_big(const float* __restrict__ emb, u16* __restrict__ embb,
              const float* __restrict__ node, const float* __restrict__ ln_g,
              const float* __restrict__ ln_b, u16* __restrict__ yb,
              const float* __restrict__ Wk, const float* __restrict__ Wv,
              const float* __restrict__ Wq, const float* __restrict__ Wg,
              const float* __restrict__ Wback,
              u16* __restrict__ WT, u16* __restrict__ WT2, u16* __restrict__ WbT) {
    const int bx = blockIdx.x;
    if (bx < 5120) {
        const size_t i = ((size_t)bx * 256 + threadIdx.x) * 8;
        const float4 a = *(const float4*)&emb[i];
        const float4 b = *(const float4*)&emb[i + 4];
        union { u16 u[8]; int4 v; } p;
        p.u[0]=f2bf(a.x); p.u[1]=f2bf(a.y); p.u[2]=f2bf(a.z); p.u[3]=f2bf(a.w);
        p.u[4]=f2bf(b.x); p.u[5]=f2bf(b.y); p.u[6]=f2bf(b.z); p.u[7]=f2bf(b.w);
        *(int4*)&embb[i] = p.v;
        return;
    }
    if (bx < 7168) {
        const int n = bx - 5120, t = threadIdx.x;
        float x = node[n * D + t];
        float s = x, sq = x * x;
        #pragma unroll
        for (int o = 32; o > 0; o >>= 1) {
            s  += __shfl_down(s, o);
            sq += __shfl_down(sq, o);
        }
        __shared__ float ss[4], sqs[4];
        if ((t & 63) == 0) { ss[t >> 6] = s; sqs[t >> 6] = sq; }
        __syncthreads();
        float S  = ss[0] + ss[1] + ss[2] + ss[3];
        float SQ = sqs[0] + sqs[1] + sqs[2] + sqs[3];
        float mu  = S * (1.f / D);
        float var = SQ * (1.f / D) - mu * mu;
        float inv = rsqrtf(var + LN_EPS);
        yb[n * D + t] = f2bf((x - mu) * inv * ln_g[t] + ln_b[t]);
        return;
    }
    // weight transpose section
    int u = bx - 7168;
    const float* W; u16* WTo; int K, kx, ny;
    if (u < 480)      { W = Wk;    WTo = WT;                       K = D_SEQ; kx = u % 40; ny = u / 40; }
    else if (u < 960) { u -= 480;  W = Wv; WTo = WT + (size_t)HDH * D_SEQ; K = D_SEQ; kx = u % 40; ny = u / 40; }
    else if (u < 1056){ u -= 960;  W = Wq; WTo = WT2;              K = D;     kx = u % 8;  ny = u / 8; }
    else if (u < 1152){ u -= 1056; W = Wg; WTo = WT2 + (size_t)HDH * D; K = D; kx = u % 8; ny = u / 8; }
    else              { u -= 1152; W = Wback; WTo = WbT;           K = HDH;   kx = u % 12; ny = u / 12; }
    const int Ncols = (W == Wback) ? D : HDH;
    const int k0 = kx * 32, n0 = ny * 32;
    __shared__ float tile[32][33];
    const int tx = threadIdx.x & 31, ty = threadIdx.x >> 5;
    #pragma unroll
    for (int i = 0; i < 32; i += 8)
        tile[ty + i][tx] = W[(size_t)(k0 + ty + i) * Ncols + n0 + tx];
    __syncthreads();
    #pragma unroll
    for (int i = 0; i < 32; i += 8)
        WTo[(size_t)(n0 + ty + i) * K + k0 + tx] = f2bf(tile[tx][ty + i]);
}

// ---------------------------------------------------------------------------
// fused K|V projection v5: m97 config — 128x128 tile, BK=32, coalesced DMA
// staging (4 lanes/row, 16B each -> 16 cache lines per 1KB DMA), 16 MFMA per
// wave per iter, 384 blocks, XCD swizzle (m-block pinned per XCD).
// K -> Kp[b][h][s][64]; V -> V4[b][h][s/4][48][4].
// ---------------------------------------------------------------------------
__global__ __launch_bounds__(256)
void kv_gemm(const u16* __restrict__ A, const u16* __restrict__ WT,
             u16* __restrict__ Kp, u16* __restrict__ V4) {
    __shared__ __align__(16) u16 As[128 * 32];   // 8 KB [row][k]
    __shared__ __align__(16) u16 Bs[128 * 32];   // 8 KB [row][k]
    const int tid = threadIdx.x;
    const int lane = tid & 63, wave = tid >> 6;
    const int glin = blockIdx.x;                 // 384
    const int xcd = glin & 7, rest = glin >> 3;  // rest < 48
    const int m0 = (xcd + 8 * (rest / 6)) * 128; // 64 M-blocks of 128 rows
    const int n0 = (rest % 6) * 128;             // 6 N-blocks
    const int wm = (wave >> 1) * 64, wn = (wave & 1) * 64;
    const int lm = lane & 15, lq = lane >> 4;

    floatx4 acc[4][4] = {};

    // coalesced staging: 4 lanes per row (16B each). Wave w covers rows
    // w*16 + lane/4 (and +64), col (lane&3)*8. LDS row-major [row][32].
    const int srow = lane >> 2, scol = (lane & 3) * 8;
    const u16* ag  = &A[(size_t)(m0 + wave * 16 + srow) * D_SEQ + scol];
    const u16* ag2 = ag + (size_t)64 * D_SEQ;
    const u16* bg  = &WT[(size_t)(n0 + wave * 16 + srow) * D_SEQ + scol];
    const u16* bg2 = bg + (size_t)64 * D_SEQ;
    u16* asb  = &As[wave * 512];
    u16* asb2 = &As[2048 + wave * 512];
    u16* bsb  = &Bs[wave * 512];
    u16* bsb2 = &Bs[2048 + wave * 512];

    for (int k0 = 0; k0 < D_SEQ; k0 += 32) {
        __syncthreads();
        load_lds16(ag + k0, asb);
        load_lds16(ag2 + k0, asb2);
        load_lds16(bg + k0, bsb);
        load_lds16(bg2 + k0, bsb2);
        __syncthreads();

        short8 af[4], bfr[4];
        #pragma unroll
        for (int i = 0; i < 4; ++i)
            af[i] = *(const short8*)&As[(wm + i * 16 + lm) * 32 + lq * 8];
        #pragma unroll
        for (int j = 0; j < 4; ++j)
            bfr[j] = *(const short8*)&Bs[(wn + j * 16 + lm) * 32 + lq * 8];
        #pragma unroll
        for (int i = 0; i < 4; ++i)
            #pragma unroll
            for (int j = 0; j < 4; ++j)
                acc[i][j] = __builtin_amdgcn_mfma_f32_16x16x32_bf16(
                    af[i], bfr[j], acc[i][j], 0, 0, 0);
    }

    #pragma unroll
    for (int i = 0; i < 4; ++i) {
        const int mrow = m0 + wm + i * 16 + lq * 4;   // emb row = b*1024+s, s%4==0
        const int bb = mrow >> 10, s = mrow & 1023;
        #pragma unroll
        for (int j = 0; j < 4; ++j) {
            const int n = n0 + wn + j * 16 + lm;
            if (n < HDH) {
                const int hh = n / 48, dd = n - hh * 48;
                u16* kp = &Kp[(((size_t)(bb * N_HEAD + hh)) * S_LEN + s) * 64 + dd];
                kp[0]   = f2bf(acc[i][j][0]);
                kp[64]  = f2bf(acc[i][j][1]);
                kp[128] = f2bf(acc[i][j][2]);
                kp[192] = f2bf(acc[i][j][3]);
            } else {
                const int nv = n - HDH;
                const int hh = nv / 48, dd = nv - hh * 48;
                ushort4v pk;   // 4 consecutive s for fixed d
                pk[0] = f2bf(acc[i][j][0]); pk[1] = f2bf(acc[i][j][1]);
                pk[2] = f2bf(acc[i][j][2]); pk[3] = f2bf(acc[i][j][3]);
                *(ushort4v*)&V4[(((size_t)(bb * N_HEAD + hh)) * (S_LEN / 4) + (s >> 2)) * 192 + dd * 4] = pk;
            }
        }
    }
}

// ---------------------------------------------------------------------------
// fused Q|gate projection (unchanged)
// ---------------------------------------------------------------------------
__global__ __launch_bounds__(256)
void qg_gemm(const u16* __restrict__ Ab, const u16* __restrict__ WT2,
             const float* __restrict__ bg, u16* __restrict__ Qb,
             float* __restrict__ gate) {
    __shared__ __align__(16) u16 As[128 * 32];
    __shared__ __align__(16) u16 Bs[128 * 32];
    const int tid = threadIdx.x;
    const int lane = tid & 63, wave = tid >> 6;
    const int wm = (wave >> 1) * 64, wn = (wave & 1) * 64;
    const int m0 = blockIdx.y * 128, n0 = blockIdx.x * 128;
    const int lm = lane & 15, lq = lane >> 4;

    floatx4 acc[4][4] = {};
    const int sr = tid >> 2;
    const int sc = (tid & 3) * 8;

    for (int k0 = 0; k0 < D; k0 += 32) {
        const int4 a0 = *(const int4*)&Ab[(size_t)(m0 + sr) * D + k0 + sc];
        const int4 a1 = *(const int4*)&Ab[(size_t)(m0 + sr + 64) * D + k0 + sc];
        const int4 b0 = *(const int4*)&WT2[(size_t)(n0 + sr) * D + k0 + sc];
        const int4 b1 = *(const int4*)&WT2[(size_t)(n0 + sr + 64) * D + k0 + sc];
        __syncthreads();
        *(int4*)&As[sr * 32 + sc] = a0;
        *(int4*)&As[(sr + 64) * 32 + sc] = a1;
        *(int4*)&Bs[sr * 32 + sc] = b0;
        *(int4*)&Bs[(sr + 64) * 32 + sc] = b1;
        __syncthreads();

        short8 af[4], bfr[4];
        #pragma unroll
        for (int i = 0; i < 4; ++i)
            af[i] = *(const short8*)&As[(wm + i * 16 + lm) * 32 + lq * 8];
        #pragma unroll
        for (int i = 0; i < 4; ++i)
            bfr[i] = *(const short8*)&Bs[(wn + i * 16 + lm) * 32 + lq * 8];
        #pragma unroll
        for (int i = 0; i < 4; ++i)
            #pragma unroll
            for (int j = 0; j < 4; ++j)
                acc[i][j] = __builtin_amdgcn_mfma_f32_16x16x32_bf16(
                    af[i], bfr[j], acc[i][j], 0, 0, 0);
    }

    #pragma unroll
    for (int i = 0; i < 4; ++i) {
        const int mb = m0 + wm + i * 16 + lq * 4;
        #pragma unroll
        for (int j = 0; j < 4; ++j) {
            const int n = n0 + wn + j * 16 + lm;
            #pragma unroll
            for (int r = 0; r < 4; ++r) {
                const int m = mb + r;
                const float v = acc[i][j][r];
                if (n < HDH) {
                    const int hh = n / 48, dd = n - hh * 48;
                    Qb[((size_t)hh * QROWS + m) * 64 + dd] = f2bf(v * QSCALE);
                } else {
                    const int ng = n - HDH;
                    gate[(size_t)m * HDH + ng] = 1.f / (1.f + __expf(-(v + bg[ng])));
                }
            }
        }
    }
}

// ---------------------------------------------------------------------------
// back-projection (bf16 MFMA) — unchanged
// ---------------------------------------------------------------------------
__global__ __launch_bounds__(256)
void back_gemm(const u16* __restrict__ Ab, const u16* __restrict__ Bt,
               const float* __restrict__ bias, const float* __restrict__ resid,
               float* __restrict__ C) {
    __shared__ __align__(16) u16 As[128 * 32];
    __shared__ __align__(16) u16 Bs[128 * 32];
    const int tid = threadIdx.x;
    const int lane = tid & 63, wave = tid >> 6;
    const int wm = (wave >> 1) * 64, wn = (wave & 1) * 64;
    const int m0 = blockIdx.y * 128, n0 = blockIdx.x * 128;
    const int lm = lane & 15, lq = lane >> 4;

    floatx4 acc[4][4] = {};
    const int sr = tid >> 2;
    const int sc = (tid & 3) * 8;

    for (int k0 = 0; k0 < HDH; k0 += 32) {
        const int4 a0 = *(const int4*)&Ab[(size_t)(m0 + sr) * HDH + k0 + sc];
        const int4 a1 = *(const int4*)&Ab[(size_t)(m0 + sr + 64) * HDH + k0 + sc];
        const int4 b0 = *(const int4*)&Bt[(size_t)(n0 + sr) * HDH + k0 + sc];
        const int4 b1 = *(const int4*)&Bt[(size_t)(n0 + sr + 64) * HDH + k0 + sc];
        __syncthreads();
        *(int4*)&As[sr * 32 + sc] = a0;
        *(int4*)&As[(sr + 64) * 32 + sc] = a1;
        *(int4*)&Bs[sr * 32 + sc] = b0;
        *(int4*)&Bs[(sr + 64) * 32 + sc] = b1;
        __syncthreads();

        short8 af[4], bfr[4];
        #pragma unroll
        for (int i = 0; i < 4; ++i)
            af[i] = *(const short8*)&As[(wm + i * 16 + lm) * 32 + lq * 8];
        #pragma unroll
        for (int i = 0; i < 4; ++i)
            bfr[i] = *(const short8*)&Bs[(wn + i * 16 + lm) * 32 + lq * 8];
        #pragma unroll
        for (int i = 0; i < 4; ++i)
            #pragma unroll
            for (int j = 0; j < 4; ++j)
                acc[i][j] = __builtin_amdgcn_mfma_f32_16x16x32_bf16(
                    af[i], bfr[j], acc[i][j], 0, 0, 0);
    }

    #pragma unroll
    for (int i = 0; i < 4; ++i) {
        const int mb = m0 + wm + i * 16 + lq * 4;
        #pragma unroll
        for (int j = 0; j < 4; ++j) {
            const int n = n0 + wn + j * 16 + lm;
            #pragma unroll
            for (int r = 0; r < 4; ++r) {
                const int m = mb + r;
                C[(size_t)m * D + n] = acc[i][j][r] + bias[n] + resid[(size_t)m * D + n];
            }
        }
    }
}

// ---------------------------------------------------------------------------
// MFMA flash attention, S-split partials, coalesced V4 reads (unchanged)
// ---------------------------------------------------------------------------
__global__ __launch_bounds__(256)
void attn_mfma(const u16* __restrict__ Qb, const u16* __restrict__ Kp,
               const u16* __restrict__ V4, const int* __restrict__ mask,
               const int* __restrict__ ranges, const int* __restrict__ wl,
               float* __restrict__ Pacc, float* __restrict__ Pl) {
    const int e = wl[blockIdx.x];
    if (e < 0) return;
    const int b = e >> 16, n0 = e & 0xffff;
    const int h = blockIdx.y, sp = blockIdx.z;
    const int nend = ranges[b + 1];
    const int NT = min(16, nend - n0);

    const int tid = threadIdx.x;
    const int wave = tid >> 6, lane = tid & 63;
    const int lm = lane & 15, lq = lane >> 4;
    const int bh = b * N_HEAD + h;

    const u16* qrow = &Qb[((size_t)h * QROWS + n0 + lm) * 64];
    const short8 qf0 = *(const short8*)&qrow[lq * 8];
    const short8 qf1 = *(const short8*)&qrow[32 + lq * 8];

    const u16* kbase = &Kp[(size_t)bh * S_LEN * 64];
    const u16* vbase = &V4[(size_t)bh * (S_LEN / 4) * 192 + (size_t)lm * 4];
    const int* mrow = &mask[b * S_LEN];

    float l_i = 0.f;
    floatx4 acc0 = {}, acc1 = {}, acc2 = {};

    const int sbase = sp * 512 + wave * 128;
    const u16* kr0 = &kbase[(size_t)(sbase + lm) * 64];
    short8 nkf0 = *(const short8*)&kr0[lq * 8];
    short8 nkf1 = *(const short8*)&kr0[32 + lq * 8];
    int4 nmv = *(const int4*)&mrow[sbase + lq * 4];
    size_t vofs = (size_t)((sbase >> 2) + lq) * 192;
    short4v nvf0 = *(const short4v*)&vbase[vofs];
    short4v nvf1 = *(const short4v*)&vbase[vofs + 64];
    short4v nvf2 = *(const short4v*)&vbase[vofs + 128];

    for (int t = 0; t < 8; ++t) {
        const short8 kf0 = nkf0, kf1 = nkf1;
        const int4 mv = nmv;
        const short4v vf0 = nvf0, vf1 = nvf1, vf2 = nvf2;
        if (t < 7) {
            const int s1 = sbase + (t + 1) * 16;
            const u16* kr = &kbase[(size_t)(s1 + lm) * 64];
            nkf0 = *(const short8*)&kr[lq * 8];
            nkf1 = *(const short8*)&kr[32 + lq * 8];
            nmv = *(const int4*)&mrow[s1 + lq * 4];
            const size_t vo = (size_t)((s1 >> 2) + lq) * 192;
            nvf0 = *(const short4v*)&vbase[vo];
            nvf1 = *(const short4v*)&vbase[vo + 64];
            nvf2 = *(const short4v*)&vbase[vo + 128];
        }

        floatx4 st = {};
        st = __builtin_amdgcn_mfma_f32_16x16x32_bf16(kf0, qf0, st, 0, 0, 0);
        st = __builtin_amdgcn_mfma_f32_16x16x32_bf16(kf1, qf1, st, 0, 0, 0);

        const float p0 = mv.x > 0 ? exp2f(st[0]) : 0.f;
        const float p1 = mv.y > 0 ? exp2f(st[1]) : 0.f;
        const float p2 = mv.z > 0 ? exp2f(st[2]) : 0.f;
        const float p3 = mv.w > 0 ? exp2f(st[3]) : 0.f;
        l_i += (p0 + p1) + (p2 + p3);

        union { __hip_bfloat162 h2[2]; short4v v; } pu;
        pu.h2[0] = __float22bfloat162_rn(make_float2(p0, p1));
        pu.h2[1] = __float22bfloat162_rn(make_float2(p2, p3));

        acc0 = __builtin_amdgcn_mfma_f32_16x16x16bf16_1k(vf0, pu.v, acc0, 0, 0, 0);
        acc1 = __builtin_amdgcn_mfma_f32_16x16x16bf16_1k(vf1, pu.v, acc1, 0, 0, 0);
        acc2 = __builtin_amdgcn_mfma_f32_16x16x16bf16_1k(vf2, pu.v, acc2, 0, 0, 0);
    }

    l_i += __shfl_xor(l_i, 16);
    l_i += __shfl_xor(l_i, 32);

    __shared__ float sl[4][64];
    __shared__ float sacc[4][3][4][64];
    sl[wave][lane] = l_i;
    #pragma unroll
    for (int r = 0; r < 4; ++r) {
        sacc[wave][0][r][lane] = acc0[r];
        sacc[wave][1][r][lane] = acc1[r];
        sacc[wave][2][r][lane] = acc2[r];
    }
    __syncthreads();
    if (wave < 3 && lm < NT) {
        const int dt = wave;
        const float L = sl[0][lane] + sl[1][lane] + sl[2][lane] + sl[3][lane];
        const size_t o = (size_t)(n0 + lm) * HDH + h * 48 + dt * 16 + lq * 4;
        float4 ov;
        ov.x = sacc[0][dt][0][lane] + sacc[1][dt][0][lane] +
               sacc[2][dt][0][lane] + sacc[3][dt][0][lane];
        ov.y = sacc[0][dt][1][lane] + sacc[1][dt][1][lane] +
               sacc[2][dt][1][lane] + sacc[3][dt][1][lane];
        ov.z = sacc[0][dt][2][lane] + sacc[1][dt][2][lane] +
               sacc[2][dt][2][lane] + sacc[3][dt][2][lane];
        ov.w = sacc[0][dt][3][lane] + sacc[1][dt][3][lane] +
               sacc[2][dt][3][lane] + sacc[3][dt][3][lane];
        *(float4*)&Pacc[(size_t)sp * N_NODE * HDH + o] = ov;
        if (wave == 0 && lq == 0)
            Pl[(size_t)sp * N_NODE * N_HEAD + (n0 + lm) * N_HEAD + h] = L;
    }
}

// ---------------------------------------------------------------------------
// fuse: gfeatb = (P0+P1) / (L0+L1) * gate  -> bf16
// ---------------------------------------------------------------------------
__global__ __launch_bounds__(256)
void fuse_kernel(const float* __restrict__ Pacc, const float* __restrict__ Pl,
                 const float* __restrict__ gate, u16* __restrict__ gfeatb) {
    const size_t i4 = ((size_t)blockIdx.x * 256 + threadIdx.x) * 4;
    const int nh = (int)(i4 / 48);               // node*8 + h
    const float4 a = *(const float4*)&Pacc[i4];
    const float4 c = *(const float4*)&Pacc[(size_t)N_NODE * HDH + i4];
    const float4 g = *(const float4*)&gate[i4];
    const float L = Pl[nh] + Pl[N_NODE * N_HEAD + nh];
    const float inv = 1.f / (L + 1e-9f);
    union { __hip_bfloat162 h2[2]; ushort4v v; } r2;
    r2.h2[0] = __float22bfloat162_rn(make_float2((a.x + c.x) * inv * g.x,
                                                 (a.y + c.y) * inv * g.y));
    r2.h2[1] = __float22bfloat162_rn(make_float2((a.z + c.z) * inv * g.z,
                                                 (a.w + c.w) * inv * g.w));
    *(ushort4v*)&gfeatb[i4] = r2.v;
}

// ---------------------------------------------------------------------------
extern "C" void kernel_launch(void* const* d_in, const int* in_sizes, int n_in,
                              void* d_out, int out_size, void* d_ws, size_t ws_size,
                              hipStream_t stream) {
    const float* node  = (const float*)d_in[0];
    const float* emb   = (const float*)d_in[1];
    const int*   mask  = (const int*)d_in[2];
    const int*   batch = (const int*)d_in[3];
    const float* ln_g  = (const float*)d_in[4];
    const float* ln_b  = (const float*)d_in[5];
    const float* Wq    = (const float*)d_in[6];
    const float* Wk    = (const float*)d_in[7];
    const float* Wv    = (const float*)d_in[8];
    const float* Wg    = (const float*)d_in[9];
    const float* bg    = (const float*)d_in[10];
    const float* Wback = (const float*)d_in[11];
    const float* bback = (const float*)d_in[12];
    float* out = (float*)d_out;

    float* ws    = (float*)d_ws;
    float* gate  = ws;                                     // 2048*384 f32
    float* Pacc  = gate + (size_t)N_NODE * HDH;            // 2*2048*384 f32
    float* Pl    = Pacc + (size_t)2 * N_NODE * HDH;        // 2*2048*8 f32
    u16*   gfeatb = (u16*)(Pl + (size_t)2 * N_NODE * N_HEAD);  // 2048*384 u16
    u16*   yb    = gfeatb + (size_t)N_NODE * HDH;          // 2048*256 u16
    u16*   WT    = yb + (size_t)N_NODE * D;                // 768*1280 u16
    u16*   WT2   = WT + (size_t)KVN * D_SEQ;               // 768*256 u16
    u16*   WbT   = WT2 + (size_t)QGN * D;                  // 256*384 u16
    u16*   Qb    = WbT + (size_t)D * HDH;                  // 8*2064*64 u16
    u16*   Kp    = Qb + (size_t)N_HEAD * QROWS * 64;       // 64*1024*64 u16
    u16*   V4    = Kp + (size_t)B_GRAPH * N_HEAD * S_LEN * 64;  // 64*256*192 u16
    u16*   embb  = V4 + (size_t)B_GRAPH * N_HEAD * (S_LEN / 4) * 192; // 8192*1280
    int*   ranges = (int*)(embb + (size_t)B_GRAPH * S_LEN * D_SEQ);
    int*   wl    = ranges + 16;

    // prep: ranges+worklist+pad (1 + 644 blocks), then bf16/ln/wtr (8416 blocks)
    prep_small<<<1 + (PAD_T + 255) / 256, 256, 0, stream>>>(batch, ranges, wl, Kp, Qb);
    prep_big<<<8416, 256, 0, stream>>>(emb, embb, node, ln_g, ln_b, yb,
                                       Wk, Wv, Wq, Wg, Wback, WT, WT2, WbT);
    kv_gemm<<<384, 256, 0, stream>>>(embb, WT, Kp, V4);
    qg_gemm<<<dim3(QGN / 128, N_NODE / 128), 256, 0, stream>>>(
        yb, WT2, bg, Qb, gate);
    attn_mfma<<<dim3(NWL, N_HEAD, 2), 256, 0, stream>>>(
        Qb, Kp, V4, mask, ranges, wl, Pacc, Pl);
    fuse_kernel<<<(N_NODE * HDH) / (256 * 4), 256, 0, stream>>>(
        Pacc, Pl, gate, gfeatb);
    back_gemm<<<dim3(D / 128, N_NODE / 128), 256, 0, stream>>>(
        gfeatb, WbT, bback, node, out);
}

// Round 14
// 187.609 us; speedup vs baseline: 1.2571x; 1.1169x over previous
//
#include <hip/hip_runtime.h>
#include <hip/hip_bf16.h>
#include <math.h>

#define D 256
#define D_SEQ 1280
#define D_HEAD 48
#define N_HEAD 8
#define HDH 384        // N_HEAD * D_HEAD
#define N_NODE 2048
#define B_GRAPH 8
#define S_LEN 1024
#define LN_EPS 1e-5f
#define QSCALE (0.14433756729740643f * 1.4426950408889634f)  // 1/sqrt(48)*log2(e)
#define KVN 768
#define QGN 768
#define QROWS (N_NODE + 16)              // padded Q rows per head
#define TPG 40         // max 16-node tiles per graph
#define NWL (TPG * 8)  // strided worklist: wl[i*8+b]
#define PAD_T 164864

typedef unsigned short u16;
typedef __attribute__((ext_vector_type(8))) short short8;
typedef __attribute__((ext_vector_type(4))) short short4v;
typedef __attribute__((ext_vector_type(4))) unsigned short ushort4v;
typedef __attribute__((ext_vector_type(4))) float floatx4;

__device__ __forceinline__ u16 f2bf(float f) {
    unsigned int x = __float_as_uint(f);
    x += 0x7fff + ((x >> 16) & 1);      // RNE to bf16
    return (u16)(x >> 16);
}

// async 16B-per-lane global->LDS DMA (wave-uniform LDS base + lane*16B)
__device__ __forceinline__ void load_lds16(const u16* g, u16* lds) {
    __builtin_amdgcn_global_load_lds(
        (const __attribute__((address_space(1))) unsigned int*)g,
        (__attribute__((address_space(3))) unsigned int*)lds, 16, 0, 0);
}

// ---------------------------------------------------------------------------
// prep: ALL preprocessing in one launch, sectioned 1-D grid.
//   [0, 5120)       : emb fp32 -> bf16 (2048 elems/block)
//   [5120, 7168)    : layernorm -> bf16 (1 node/block)
//   [7168, 8416)    : weight transposes (Wk 480 | Wv 480 | Wq 96 | Wg 96 | Wb 96)
//   [8416]          : ranges + worklist
//   (8416, 9061)    : pad zeroing (Kp cols 48..63; Qb cols 48..63; Qb pad rows)
// ---------------------------------------------------------------------------
__global__ __launch_bounds__(256)
void prep(const float* __restrict__ emb, u16* __restrict__ embb,
          const float* __restrict__ node, const float* __restrict__ ln_g,
          const float* __restrict__ ln_b, u16* __restrict__ yb,
          const float* __restrict__ Wk, const float* __restrict__ Wv,
          const float* __restrict__ Wq, const float* __restrict__ Wg,
          const float* __restrict__ Wback,
          u16* __restrict__ WT, u16* __restrict__ WT2, u16* __restrict__ WbT,
          const int* __restrict__ batch, int* __restrict__ ranges,
          int* __restrict__ wl, u16* __restrict__ Kp, u16* __restrict__ Qb) {
    const int bx = blockIdx.x;
    if (bx < 5120) {
        const size_t i = ((size_t)bx * 256 + threadIdx.x) * 8;
        const float4 a = *(const float4*)&emb[i];
        const float4 b = *(const float4*)&emb[i + 4];
        union { u16 u[8]; int4 v; } p;
        p.u[0]=f2bf(a.x); p.u[1]=f2bf(a.y); p.u[2]=f2bf(a.z); p.u[3]=f2bf(a.w);
        p.u[4]=f2bf(b.x); p.u[5]=f2bf(b.y); p.u[6]=f2bf(b.z); p.u[7]=f2bf(b.w);
        *(int4*)&embb[i] = p.v;
        return;
    }
    if (bx < 7168) {
        const int n = bx - 5120, t = threadIdx.x;
        float x = node[n * D + t];
        float s = x, sq = x * x;
        #pragma unroll
        for (int o = 32; o > 0; o >>= 1) {
            s  += __shfl_down(s, o);
            sq += __shfl_down(sq, o);
        }
        __shared__ float ss[4], sqs[4];
        if ((t & 63) == 0) { ss[t >> 6] = s; sqs[t >> 6] = sq; }
        __syncthreads();
        float S  = ss[0] + ss[1] + ss[2] + ss[3];
        float SQ = sqs[0] + sqs[1] + sqs[2] + sqs[3];
        float mu  = S * (1.f / D);
        float var = SQ * (1.f / D) - mu * mu;
        float inv = rsqrtf(var + LN_EPS);
        yb[n * D + t] = f2bf((x - mu) * inv * ln_g[t] + ln_b[t]);
        return;
    }
    if (bx < 8416) {
        int u = bx - 7168;
        const float* W; u16* WTo; int K, kx, ny, Ncols;
        if (u < 480)      { W = Wk;    WTo = WT;                       K = D_SEQ; Ncols = HDH; kx = u % 40; ny = u / 40; }
        else if (u < 960) { u -= 480;  W = Wv; WTo = WT + (size_t)HDH * D_SEQ; K = D_SEQ; Ncols = HDH; kx = u % 40; ny = u / 40; }
        else if (u < 1056){ u -= 960;  W = Wq; WTo = WT2;              K = D;   Ncols = HDH; kx = u % 8;  ny = u / 8; }
        else if (u < 1152){ u -= 1056; W = Wg; WTo = WT2 + (size_t)HDH * D; K = D; Ncols = HDH; kx = u % 8; ny = u / 8; }
        else              { u -= 1152; W = Wback; WTo = WbT;           K = HDH; Ncols = D;   kx = u % 12; ny = u / 12; }
        const int k0 = kx * 32, n0 = ny * 32;
        __shared__ float tile[32][33];
        const int tx = threadIdx.x & 31, ty = threadIdx.x >> 5;
        #pragma unroll
        for (int i = 0; i < 32; i += 8)
            tile[ty + i][tx] = W[(size_t)(k0 + ty + i) * Ncols + n0 + tx];
        __syncthreads();
        #pragma unroll
        for (int i = 0; i < 32; i += 8)
            WTo[(size_t)(n0 + ty + i) * K + k0 + tx] = f2bf(tile[tx][ty + i]);
        return;
    }
    if (bx == 8416) {
        int t = threadIdx.x;
        if (t <= B_GRAPH) {
            int lo = 0, hi = N_NODE;
            while (lo < hi) {
                int mid = (lo + hi) >> 1;
                if (batch[mid] < t) lo = mid + 1; else hi = mid;
            }
            ranges[t] = lo;
        }
        __syncthreads();
        if (t < B_GRAPH) {
            const int s = ranges[t];
            const int ntile = (ranges[t + 1] - s + 15) >> 4;
            for (int i = 0; i < TPG; ++i)
                wl[i * 8 + t] = (i < ntile) ? ((t << 16) | (s + i * 16)) : -1;
        }
        return;
    }
    const int t = (bx - 8417) * 256 + threadIdx.x;
    const int4 z = {0, 0, 0, 0};
    if (t < 131072) {
        const int row = t >> 1, half = t & 1;
        *(int4*)&Kp[(size_t)row * 64 + 48 + half * 8] = z;
    } else if (t < 164096) {
        const int u = t - 131072;
        const int row = u >> 1, half = u & 1;
        *(int4*)&Qb[(size_t)row * 64 + 48 + half * 8] = z;
    } else {
        const int u = t - 164096;
        const int row = u / 6, c = u - row * 6;      // row in [0,128)
        const int hh = row >> 4, m = 2048 + (row & 15);
        *(int4*)&Qb[((size_t)hh * QROWS + m) * 64 + c * 8] = z;
    }
}

// ---------------------------------------------------------------------------
// kvqg_gemm: blocks 0..383 = K|V projection (m97 config: 128x128 tile, BK=32,
// coalesced DMA staging, XCD swizzle); blocks 384..479 = Q|gate projection.
// Both depend only on prep; qg's tail hides under kv.
// ---------------------------------------------------------------------------
__global__ __launch_bounds__(256)
void kvqg_gemm(const u16* __restrict__ A, const u16* __restrict__ WT,
               u16* __restrict__ Kp, u16* __restrict__ V4,
               const u16* __restrict__ Ab, const u16* __restrict__ WT2,
               const float* __restrict__ bg, u16* __restrict__ Qb,
               float* __restrict__ gate) {
    __shared__ __align__(16) u16 As[128 * 32];   // 8 KB
    __shared__ __align__(16) u16 Bs[128 * 32];   // 8 KB
    const int tid = threadIdx.x;
    const int lane = tid & 63, wave = tid >> 6;
    const int wm64 = (wave >> 1) * 64, wn64 = (wave & 1) * 64;
    const int lm = lane & 15, lq = lane >> 4;

    if (blockIdx.x < 384) {
        // ---- K|V path ----
        const int glin = blockIdx.x;
        const int xcd = glin & 7, rest = glin >> 3;
        const int m0 = (xcd + 8 * (rest / 6)) * 128;
        const int n0 = (rest % 6) * 128;

        floatx4 acc[4][4] = {};

        const int srow = lane >> 2, scol = (lane & 3) * 8;
        const u16* ag  = &A[(size_t)(m0 + wave * 16 + srow) * D_SEQ + scol];
        const u16* ag2 = ag + (size_t)64 * D_SEQ;
        const u16* bgp = &WT[(size_t)(n0 + wave * 16 + srow) * D_SEQ + scol];
        const u16* bg2 = bgp + (size_t)64 * D_SEQ;
        u16* asb  = &As[wave * 512];
        u16* asb2 = &As[2048 + wave * 512];
        u16* bsb  = &Bs[wave * 512];
        u16* bsb2 = &Bs[2048 + wave * 512];

        for (int k0 = 0; k0 < D_SEQ; k0 += 32) {
            __syncthreads();
            load_lds16(ag + k0, asb);
            load_lds16(ag2 + k0, asb2);
            load_lds16(bgp + k0, bsb);
            load_lds16(bg2 + k0, bsb2);
            __syncthreads();

            short8 af[4], bfr[4];
            #pragma unroll
            for (int i = 0; i < 4; ++i)
                af[i] = *(const short8*)&As[(wm64 + i * 16 + lm) * 32 + lq * 8];
            #pragma unroll
            for (int j = 0; j < 4; ++j)
                bfr[j] = *(const short8*)&Bs[(wn64 + j * 16 + lm) * 32 + lq * 8];
            #pragma unroll
            for (int i = 0; i < 4; ++i)
                #pragma unroll
                for (int j = 0; j < 4; ++j)
                    acc[i][j] = __builtin_amdgcn_mfma_f32_16x16x32_bf16(
                        af[i], bfr[j], acc[i][j], 0, 0, 0);
        }

        #pragma unroll
        for (int i = 0; i < 4; ++i) {
            const int mrow = m0 + wm64 + i * 16 + lq * 4;   // b*1024+s, s%4==0
            const int bb = mrow >> 10, s = mrow & 1023;
            #pragma unroll
            for (int j = 0; j < 4; ++j) {
                const int n = n0 + wn64 + j * 16 + lm;
                if (n < HDH) {
                    const int hh = n / 48, dd = n - hh * 48;
                    u16* kp = &Kp[(((size_t)(bb * N_HEAD + hh)) * S_LEN + s) * 64 + dd];
                    kp[0]   = f2bf(acc[i][j][0]);
                    kp[64]  = f2bf(acc[i][j][1]);
                    kp[128] = f2bf(acc[i][j][2]);
                    kp[192] = f2bf(acc[i][j][3]);
                } else {
                    const int nv = n - HDH;
                    const int hh = nv / 48, dd = nv - hh * 48;
                    ushort4v pk;
                    pk[0] = f2bf(acc[i][j][0]); pk[1] = f2bf(acc[i][j][1]);
                    pk[2] = f2bf(acc[i][j][2]); pk[3] = f2bf(acc[i][j][3]);
                    *(ushort4v*)&V4[(((size_t)(bb * N_HEAD + hh)) * (S_LEN / 4) + (s >> 2)) * 192 + dd * 4] = pk;
                }
            }
        }
        return;
    }

    // ---- Q|gate path ----
    {
        const int u = blockIdx.x - 384;          // 0..95
        const int m0 = (u / 6) * 128, n0 = (u % 6) * 128;

        floatx4 acc[4][4] = {};
        const int sr = tid >> 2;
        const int sc = (tid & 3) * 8;

        for (int k0 = 0; k0 < D; k0 += 32) {
            const int4 a0 = *(const int4*)&Ab[(size_t)(m0 + sr) * D + k0 + sc];
            const int4 a1 = *(const int4*)&Ab[(size_t)(m0 + sr + 64) * D + k0 + sc];
            const int4 b0 = *(const int4*)&WT2[(size_t)(n0 + sr) * D + k0 + sc];
            const int4 b1 = *(const int4*)&WT2[(size_t)(n0 + sr + 64) * D + k0 + sc];
            __syncthreads();
            *(int4*)&As[sr * 32 + sc] = a0;
            *(int4*)&As[(sr + 64) * 32 + sc] = a1;
            *(int4*)&Bs[sr * 32 + sc] = b0;
            *(int4*)&Bs[(sr + 64) * 32 + sc] = b1;
            __syncthreads();

            short8 af[4], bfr[4];
            #pragma unroll
            for (int i = 0; i < 4; ++i)
                af[i] = *(const short8*)&As[(wm64 + i * 16 + lm) * 32 + lq * 8];
            #pragma unroll
            for (int i = 0; i < 4; ++i)
                bfr[i] = *(const short8*)&Bs[(wn64 + i * 16 + lm) * 32 + lq * 8];
            #pragma unroll
            for (int i = 0; i < 4; ++i)
                #pragma unroll
                for (int j = 0; j < 4; ++j)
                    acc[i][j] = __builtin_amdgcn_mfma_f32_16x16x32_bf16(
                        af[i], bfr[j], acc[i][j], 0, 0, 0);
        }

        #pragma unroll
        for (int i = 0; i < 4; ++i) {
            const int mb = m0 + wm64 + i * 16 + lq * 4;
            #pragma unroll
            for (int j = 0; j < 4; ++j) {
                const int n = n0 + wn64 + j * 16 + lm;
                #pragma unroll
                for (int r = 0; r < 4; ++r) {
                    const int m = mb + r;
                    const float v = acc[i][j][r];
                    if (n < HDH) {
                        const int hh = n / 48, dd = n - hh * 48;
                        Qb[((size_t)hh * QROWS + m) * 64 + dd] = f2bf(v * QSCALE);
                    } else {
                        const int ng = n - HDH;
                        gate[(size_t)m * HDH + ng] = 1.f / (1.f + __expf(-(v + bg[ng])));
                    }
                }
            }
        }
    }
}

// ---------------------------------------------------------------------------
// back-projection (bf16 MFMA) — unchanged
// ---------------------------------------------------------------------------
__global__ __launch_bounds__(256)
void back_gemm(const u16* __restrict__ Ab, const u16* __restrict__ Bt,
               const float* __restrict__ bias, const float* __restrict__ resid,
               float* __restrict__ C) {
    __shared__ __align__(16) u16 As[128 * 32];
    __shared__ __align__(16) u16 Bs[128 * 32];
    const int tid = threadIdx.x;
    const int lane = tid & 63, wave = tid >> 6;
    const int wm = (wave >> 1) * 64, wn = (wave & 1) * 64;
    const int m0 = blockIdx.y * 128, n0 = blockIdx.x * 128;
    const int lm = lane & 15, lq = lane >> 4;

    floatx4 acc[4][4] = {};
    const int sr = tid >> 2;
    const int sc = (tid & 3) * 8;

    for (int k0 = 0; k0 < HDH; k0 += 32) {
        const int4 a0 = *(const int4*)&Ab[(size_t)(m0 + sr) * HDH + k0 + sc];
        const int4 a1 = *(const int4*)&Ab[(size_t)(m0 + sr + 64) * HDH + k0 + sc];
        const int4 b0 = *(const int4*)&Bt[(size_t)(n0 + sr) * HDH + k0 + sc];
        const int4 b1 = *(const int4*)&Bt[(size_t)(n0 + sr + 64) * HDH + k0 + sc];
        __syncthreads();
        *(int4*)&As[sr * 32 + sc] = a0;
        *(int4*)&As[(sr + 64) * 32 + sc] = a1;
        *(int4*)&Bs[sr * 32 + sc] = b0;
        *(int4*)&Bs[(sr + 64) * 32 + sc] = b1;
        __syncthreads();

        short8 af[4], bfr[4];
        #pragma unroll
        for (int i = 0; i < 4; ++i)
            af[i] = *(const short8*)&As[(wm + i * 16 + lm) * 32 + lq * 8];
        #pragma unroll
        for (int i = 0; i < 4; ++i)
            bfr[i] = *(const short8*)&Bs[(wn + i * 16 + lm) * 32 + lq * 8];
        #pragma unroll
        for (int i = 0; i < 4; ++i)
            #pragma unroll
            for (int j = 0; j < 4; ++j)
                acc[i][j] = __builtin_amdgcn_mfma_f32_16x16x32_bf16(
                    af[i], bfr[j], acc[i][j], 0, 0, 0);
    }

    #pragma unroll
    for (int i = 0; i < 4; ++i) {
        const int mb = m0 + wm + i * 16 + lq * 4;
        #pragma unroll
        for (int j = 0; j < 4; ++j) {
            const int n = n0 + wn + j * 16 + lm;
            #pragma unroll
            for (int r = 0; r < 4; ++r) {
                const int m = mb + r;
                C[(size_t)m * D + n] = acc[i][j][r] + bias[n] + resid[(size_t)m * D + n];
            }
        }
    }
}

// ---------------------------------------------------------------------------
// MFMA flash attention, S-split partials, coalesced V4 reads, DEPTH-2
// register prefetch (loads for t+2 issued while computing t).
// ---------------------------------------------------------------------------
struct Pref {
    short8 k0, k1;
    int4 mv;
    short4v v0, v1, v2;
};

__device__ __forceinline__ Pref ldpref(const u16* kbase, const u16* vbase,
                                       const int* mrow, int s, int lm, int lq) {
    Pref p;
    const u16* kr = &kbase[(size_t)(s + lm) * 64];
    p.k0 = *(const short8*)&kr[lq * 8];
    p.k1 = *(const short8*)&kr[32 + lq * 8];
    p.mv = *(const int4*)&mrow[s + lq * 4];
    const size_t vo = (size_t)((s >> 2) + lq) * 192;
    p.v0 = *(const short4v*)&vbase[vo];
    p.v1 = *(const short4v*)&vbase[vo + 64];
    p.v2 = *(const short4v*)&vbase[vo + 128];
    return p;
}

__global__ __launch_bounds__(256)
void attn_mfma(const u16* __restrict__ Qb, const u16* __restrict__ Kp,
               const u16* __restrict__ V4, const int* __restrict__ mask,
               const int* __restrict__ ranges, const int* __restrict__ wl,
               float* __restrict__ Pacc, float* __restrict__ Pl) {
    const int e = wl[blockIdx.x];
    if (e < 0) return;
    const int b = e >> 16, n0 = e & 0xffff;
    const int h = blockIdx.y, sp = blockIdx.z;
    const int nend = ranges[b + 1];
    const int NT = min(16, nend - n0);

    const int tid = threadIdx.x;
    const int wave = tid >> 6, lane = tid & 63;
    const int lm = lane & 15, lq = lane >> 4;
    const int bh = b * N_HEAD + h;

    const u16* qrow = &Qb[((size_t)h * QROWS + n0 + lm) * 64];
    const short8 qf0 = *(const short8*)&qrow[lq * 8];
    const short8 qf1 = *(const short8*)&qrow[32 + lq * 8];

    const u16* kbase = &Kp[(size_t)bh * S_LEN * 64];
    const u16* vbase = &V4[(size_t)bh * (S_LEN / 4) * 192 + (size_t)lm * 4];
    const int* mrow = &mask[b * S_LEN];

    float l_i = 0.f;
    floatx4 acc0 = {}, acc1 = {}, acc2 = {};

    const int sbase = sp * 512 + wave * 128;
    Pref pf[2];
    pf[0] = ldpref(kbase, vbase, mrow, sbase, lm, lq);
    pf[1] = ldpref(kbase, vbase, mrow, sbase + 16, lm, lq);

    #pragma unroll
    for (int t = 0; t < 8; ++t) {
        const Pref cur = pf[t & 1];
        if (t < 6)
            pf[t & 1] = ldpref(kbase, vbase, mrow, sbase + (t + 2) * 16, lm, lq);

        floatx4 st = {};
        st = __builtin_amdgcn_mfma_f32_16x16x32_bf16(cur.k0, qf0, st, 0, 0, 0);
        st = __builtin_amdgcn_mfma_f32_16x16x32_bf16(cur.k1, qf1, st, 0, 0, 0);

        const float p0 = cur.mv.x > 0 ? exp2f(st[0]) : 0.f;
        const float p1 = cur.mv.y > 0 ? exp2f(st[1]) : 0.f;
        const float p2 = cur.mv.z > 0 ? exp2f(st[2]) : 0.f;
        const float p3 = cur.mv.w > 0 ? exp2f(st[3]) : 0.f;
        l_i += (p0 + p1) + (p2 + p3);

        union { __hip_bfloat162 h2[2]; short4v v; } pu;
        pu.h2[0] = __float22bfloat162_rn(make_float2(p0, p1));
        pu.h2[1] = __float22bfloat162_rn(make_float2(p2, p3));

        acc0 = __builtin_amdgcn_mfma_f32_16x16x16bf16_1k(cur.v0, pu.v, acc0, 0, 0, 0);
        acc1 = __builtin_amdgcn_mfma_f32_16x16x16bf16_1k(cur.v1, pu.v, acc1, 0, 0, 0);
        acc2 = __builtin_amdgcn_mfma_f32_16x16x16bf16_1k(cur.v2, pu.v, acc2, 0, 0, 0);
    }

    l_i += __shfl_xor(l_i, 16);
    l_i += __shfl_xor(l_i, 32);

    __shared__ float sl[4][64];
    __shared__ float sacc[4][3][4][64];
    sl[wave][lane] = l_i;
    #pragma unroll
    for (int r = 0; r < 4; ++r) {
        sacc[wave][0][r][lane] = acc0[r];
        sacc[wave][1][r][lane] = acc1[r];
        sacc[wave][2][r][lane] = acc2[r];
    }
    __syncthreads();
    if (wave < 3 && lm < NT) {
        const int dt = wave;
        const float L = sl[0][lane] + sl[1][lane] + sl[2][lane] + sl[3][lane];
        const size_t o = (size_t)(n0 + lm) * HDH + h * 48 + dt * 16 + lq * 4;
        float4 ov;
        ov.x = sacc[0][dt][0][lane] + sacc[1][dt][0][lane] +
               sacc[2][dt][0][lane] + sacc[3][dt][0][lane];
        ov.y = sacc[0][dt][1][lane] + sacc[1][dt][1][lane] +
               sacc[2][dt][1][lane] + sacc[3][dt][1][lane];
        ov.z = sacc[0][dt][2][lane] + sacc[1][dt][2][lane] +
               sacc[2][dt][2][lane] + sacc[3][dt][2][lane];
        ov.w = sacc[0][dt][3][lane] + sacc[1][dt][3][lane] +
               sacc[2][dt][3][lane] + sacc[3][dt][3][lane];
        *(float4*)&Pacc[(size_t)sp * N_NODE * HDH + o] = ov;
        if (wave == 0 && lq == 0)
            Pl[(size_t)sp * N_NODE * N_HEAD + (n0 + lm) * N_HEAD + h] = L;
    }
}

// ---------------------------------------------------------------------------
// fuse: gfeatb = (P0+P1) / (L0+L1) * gate  -> bf16
// ---------------------------------------------------------------------------
__global__ __launch_bounds__(256)
void fuse_kernel(const float* __restrict__ Pacc, const float* __restrict__ Pl,
                 const float* __restrict__ gate, u16* __restrict__ gfeatb) {
    const size_t i4 = ((size_t)blockIdx.x * 256 + threadIdx.x) * 4;
    const int nh = (int)(i4 / 48);               // node*8 + h
    const float4 a = *(const float4*)&Pacc[i4];
    const float4 c = *(const float4*)&Pacc[(size_t)N_NODE * HDH + i4];
    const float4 g = *(const float4*)&gate[i4];
    const float L = Pl[nh] + Pl[N_NODE * N_HEAD + nh];
    const float inv = 1.f / (L + 1e-9f);
    union { __hip_bfloat162 h2[2]; ushort4v v; } r2;
    r2.h2[0] = __float22bfloat162_rn(make_float2((a.x + c.x) * inv * g.x,
                                                 (a.y + c.y) * inv * g.y));
    r2.h2[1] = __float22bfloat162_rn(make_float2((a.z + c.z) * inv * g.z,
                                                 (a.w + c.w) * inv * g.w));
    *(ushort4v*)&gfeatb[i4] = r2.v;
}

// ---------------------------------------------------------------------------
extern "C" void kernel_launch(void* const* d_in, const int* in_sizes, int n_in,
                              void* d_out, int out_size, void* d_ws, size_t ws_size,
                              hipStream_t stream) {
    const float* node  = (const float*)d_in[0];
    const float* emb   = (const float*)d_in[1];
    const int*   mask  = (const int*)d_in[2];
    const int*   batch = (const int*)d_in[3];
    const float* ln_g  = (const float*)d_in[4];
    const float* ln_b  = (const float*)d_in[5];
    const float* Wq    = (const float*)d_in[6];
    const float* Wk    = (const float*)d_in[7];
    const float* Wv    = (const float*)d_in[8];
    const float* Wg    = (const float*)d_in[9];
    const float* bg    = (const float*)d_in[10];
    const float* Wback = (const float*)d_in[11];
    const float* bback = (const float*)d_in[12];
    float* out = (float*)d_out;

    float* ws    = (float*)d_ws;
    float* gate  = ws;                                     // 2048*384 f32
    float* Pacc  = gate + (size_t)N_NODE * HDH;            // 2*2048*384 f32
    float* Pl    = Pacc + (size_t)2 * N_NODE * HDH;        // 2*2048*8 f32
    u16*   gfeatb = (u16*)(Pl + (size_t)2 * N_NODE * N_HEAD);  // 2048*384 u16
    u16*   yb    = gfeatb + (size_t)N_NODE * HDH;          // 2048*256 u16
    u16*   WT    = yb + (size_t)N_NODE * D;                // 768*1280 u16
    u16*   WT2   = WT + (size_t)KVN * D_SEQ;               // 768*256 u16
    u16*   WbT   = WT2 + (size_t)QGN * D;                  // 256*384 u16
    u16*   Qb    = WbT + (size_t)D * HDH;                  // 8*2064*64 u16
    u16*   Kp    = Qb + (size_t)N_HEAD * QROWS * 64;       // 64*1024*64 u16
    u16*   V4    = Kp + (size_t)B_GRAPH * N_HEAD * S_LEN * 64;  // 64*256*192 u16
    u16*   embb  = V4 + (size_t)B_GRAPH * N_HEAD * (S_LEN / 4) * 192; // 8192*1280
    int*   ranges = (int*)(embb + (size_t)B_GRAPH * S_LEN * D_SEQ);
    int*   wl    = ranges + 16;

    // 5 launches total
    prep<<<8417 + PAD_T / 256, 256, 0, stream>>>(
        emb, embb, node, ln_g, ln_b, yb, Wk, Wv, Wq, Wg, Wback,
        WT, WT2, WbT, batch, ranges, wl, Kp, Qb);
    kvqg_gemm<<<480, 256, 0, stream>>>(embb, WT, Kp, V4, yb, WT2, bg, Qb, gate);
    attn_mfma<<<dim3(NWL, N_HEAD, 2), 256, 0, stream>>>(
        Qb, Kp, V4, mask, ranges, wl, Pacc, Pl);
    fuse_kernel<<<(N_NODE * HDH) / (256 * 4), 256, 0, stream>>>(
        Pacc, Pl, gate, gfeatb);
    back_gemm<<<dim3(D / 128, N_NODE / 128), 256, 0, stream>>>(
        gfeatb, WbT, bback, node, out);
}